// Round 2
// baseline (712.790 us; speedup 1.0000x reference)
//
#include <hip/hip_runtime.h>
#include <hip/hip_bf16.h>
#include <cstdint>

typedef unsigned short u16;
typedef __bf16 v8bf __attribute__((ext_vector_type(8)));
typedef short v4s __attribute__((ext_vector_type(4)));
typedef float v4f __attribute__((ext_vector_type(4)));

__device__ __forceinline__ u16 f2bf(float f) {
  union { float f; uint32_t u; } v; v.f = f;
  return (u16)((v.u + 0x7fffu + ((v.u >> 16) & 1u)) >> 16);
}
__device__ __forceinline__ float bf2f(u16 u) {
  union { uint32_t u; float f; } v; v.u = ((uint32_t)u) << 16; return v.f;
}

// async global->LDS, 16B per lane; LDS dest = wave-uniform base + lane*16
#define GLL16(gsrc, ldst) \
  __builtin_amdgcn_global_load_lds((__attribute__((address_space(1))) void*)(gsrc), \
      (__attribute__((address_space(3))) void*)(ldst), 16, 0, 0)

// XCD-aware tile map (64 bm-tiles, M=8192): XCD (blk%8) owns a contiguous
// 8-row bm band; co-resident blocks sweep bn in lockstep.
#define TILE_MAP(blk, bm, bn) \
  int bm = ((blk) & 7) * 8 + (((blk) >> 3) & 7); \
  int bn = (blk) >> 6;

// ---------------- GEMM core (128x128 tile, BK=64, XOR-swizzled LDS) ----------------
// kept for kernels that must run at 256 threads (attn_proj fusion) or with
// small N-tile counts (fc2, projadd).
__device__ __forceinline__ void gemm_core(
    const u16* __restrict__ A, const u16* __restrict__ Bt, int K,
    char* la, char* lb, int bm, int bn, int tid, v4f acc[4][4])
{
  int wv = tid >> 6, lane = tid & 63, quad = lane >> 4, lc = lane & 15;
  int wm = wv & 1, wn = wv >> 1;
  for (int kt = 0; kt < K; kt += 64) {
    __syncthreads();
    #pragma unroll
    for (int c0 = 0; c0 < 4; ++c0) {
      int chunk = wv*4 + c0;
      int off = chunk*1024 + lane*16;
      int row = off >> 7;
      int sc  = (off >> 4) & 7;
      int lg  = sc ^ (row & 7);
      GLL16(A  + (size_t)(bm*128 + row) * K + kt + lg*8, la + chunk*1024);
      GLL16(Bt + (size_t)(bn*128 + row) * K + kt + lg*8, lb + chunk*1024);
    }
    __syncthreads();
    #pragma unroll
    for (int kc = 0; kc < 2; ++kc) {
      v8bf af[4], bfr[4];
      #pragma unroll
      for (int r = 0; r < 4; ++r) {
        int row = wm*64 + r*16 + lc;
        int sc = (kc*4 + quad) ^ (row & 7);
        af[r] = *(const v8bf*)(la + row*128 + sc*16);
      }
      #pragma unroll
      for (int c = 0; c < 4; ++c) {
        int row = wn*64 + c*16 + lc;
        int sc = (kc*4 + quad) ^ (row & 7);
        bfr[c] = *(const v8bf*)(lb + row*128 + sc*16);
      }
      #pragma unroll
      for (int r = 0; r < 4; ++r)
        #pragma unroll
        for (int c = 0; c < 4; ++c)
          acc[r][c] = __builtin_amdgcn_mfma_f32_16x16x32_bf16(af[r], bfr[c], acc[r][c], 0, 0, 0);
    }
  }
}

// ---------------- GEMM core v2: 256x256 tile, BK=64, 8-phase counted-vmcnt ----------------
// 512 threads = 8 waves (2M x 4N), per-wave 128x64 output (acc[8][4]).
// LDS 128 KiB: A [2buf][256][64]bf16 @0, B same @65536. XOR chunk swizzle.
// LDS liveness per tile t (computing from bsel):
//   A halves read at ph1 (qm0) AND ph3 (qm1)  -> A dead after ph3
//   B halves read at ph1 (qn0) AND ph2 (qn1)  -> B dead after ph2
// Staging (all of tile t+2 -> bsel, during tile t):
//   ph3: B half0+half1 (4 loads)   ph4: A half0+half1 (4 loads)
// Gate: vmcnt(8) at ph4 end => t+2's 8 loads may fly; t+1's 8 loads (issued
// during tile t-1, 4-6 phases ago) must have landed. vmcnt(0) at t==NT-2.
template<int NT>
__device__ __forceinline__ void gemm8_core(
    const u16* __restrict__ A, const u16* __restrict__ Bt,
    char* lds, int bm, int bn, int tid, v4f acc[8][4])
{
  constexpr int K = NT * 64;
  int wid = tid >> 6, lane = tid & 63, quad = lane >> 4, lc = lane & 15;
  int wm = wid >> 2, wn = wid & 3;

  // staging geometry: per wave 2 chunks (1 KiB each) per half-tile
  int ch0 = wid*2, ch1 = wid*2 + 1;
  int r0 = ch0*8 + (lane >> 3), r1 = ch1*8 + (lane >> 3);
  int lg0 = (lane & 7) ^ (r0 & 7), lg1 = (lane & 7) ^ (r1 & 7);
  const u16* gA0 = A  + (size_t)(bm*256 + r0) * K + lg0*8;
  const u16* gA1 = A  + (size_t)(bm*256 + r1) * K + lg1*8;
  const u16* gB0 = Bt + (size_t)(bn*256 + r0) * K + lg0*8;
  const u16* gB1 = Bt + (size_t)(bn*256 + r1) * K + lg1*8;
  int dA0 = ch0*1024, dA1 = ch1*1024;

  auto STAGE_A = [&](int h, int tile, int buf) {
    GLL16(gA0 + (size_t)h*128*K + tile*64, lds + buf*32768 + h*16384 + dA0);
    GLL16(gA1 + (size_t)h*128*K + tile*64, lds + buf*32768 + h*16384 + dA1);
  };
  auto STAGE_B = [&](int h, int tile, int buf) {
    GLL16(gB0 + (size_t)h*128*K + tile*64, lds + 65536 + buf*32768 + h*16384 + dA0);
    GLL16(gB1 + (size_t)h*128*K + tile*64, lds + 65536 + buf*32768 + h*16384 + dA1);
  };

  // ds_read bases: row&7 == lc&7 for all fragment rows (row = 16-mult + lc)
  int s0 = quad ^ (lc & 7);
  const char* rA0 = lds + ((wm*128 + lc)*128 + s0*16);
  const char* rA1 = lds + ((wm*128 + lc)*128 + (s0^4)*16);
  const char* rB0 = lds + 65536 + ((wn*64 + lc)*128 + s0*16);
  const char* rB1 = lds + 65536 + ((wn*64 + lc)*128 + (s0^4)*16);

  v8bf a[4][2], b0[2][2], b1[2][2];

#define RD_A(qm) do { _Pragma("unroll") for (int mf = 0; mf < 4; ++mf) { \
    a[mf][0] = *(const v8bf*)(rA0 + bsel*32768 + (qm)*8192 + mf*2048); \
    a[mf][1] = *(const v8bf*)(rA1 + bsel*32768 + (qm)*8192 + mf*2048); } } while(0)
#define RD_B(qn, bb) do { _Pragma("unroll") for (int nf = 0; nf < 2; ++nf) { \
    bb[nf][0] = *(const v8bf*)(rB0 + bsel*32768 + (qn)*4096 + nf*2048); \
    bb[nf][1] = *(const v8bf*)(rB1 + bsel*32768 + (qn)*4096 + nf*2048); } } while(0)
#define MFMAQ(qm, bb, qn) do { \
    __builtin_amdgcn_s_setprio(1); \
    _Pragma("unroll") for (int mf = 0; mf < 4; ++mf) \
    _Pragma("unroll") for (int nf = 0; nf < 2; ++nf) \
    _Pragma("unroll") for (int kc = 0; kc < 2; ++kc) \
      acc[(qm)*4+mf][(qn)*2+nf] = __builtin_amdgcn_mfma_f32_16x16x32_bf16( \
          a[mf][kc], bb[nf][kc], acc[(qm)*4+mf][(qn)*2+nf], 0, 0, 0); \
    __builtin_amdgcn_s_setprio(0); } while(0)
#define LGKM0 do { asm volatile("s_waitcnt lgkmcnt(0)" ::: "memory"); \
    __builtin_amdgcn_sched_barrier(0); } while(0)

#define GROUP(t, bs) do { \
    const int bsel = (bs); \
    /* ph1 */ \
    RD_A(0); RD_B(0, b0); \
    __builtin_amdgcn_s_barrier(); LGKM0; \
    MFMAQ(0, b0, 0); \
    __builtin_amdgcn_s_barrier(); \
    /* ph2 */ \
    RD_B(1, b1); \
    __builtin_amdgcn_s_barrier(); LGKM0; \
    MFMAQ(0, b1, 1); \
    __builtin_amdgcn_s_barrier(); \
    /* ph3: stage (t+2).B -> bsel (B region dead after ph2) */ \
    RD_A(1); \
    if ((t)+2 < NT) { STAGE_B(0, (t)+2, bsel); STAGE_B(1, (t)+2, bsel); } \
    __builtin_amdgcn_s_barrier(); LGKM0; \
    MFMAQ(1, b1, 1); \
    __builtin_amdgcn_s_barrier(); \
    /* ph4: stage (t+2).A -> bsel (A region dead after ph3) */ \
    if ((t)+2 < NT) { STAGE_A(0, (t)+2, bsel); STAGE_A(1, (t)+2, bsel); } \
    MFMAQ(1, b0, 0); \
    if ((t)+2 < NT)       asm volatile("s_waitcnt vmcnt(8)" ::: "memory"); \
    else if ((t)+2 == NT) asm volatile("s_waitcnt vmcnt(0)" ::: "memory"); \
    __builtin_amdgcn_s_barrier(); \
  } while(0)

  // prologue: tiles 0 and 1 fully staged (16 loads); wait tile 0 (8 newest fly)
  STAGE_B(0, 0, 0); STAGE_B(1, 0, 0);
  STAGE_A(0, 0, 0); STAGE_A(1, 0, 0);
  STAGE_B(0, 1, 1); STAGE_B(1, 1, 1);
  STAGE_A(0, 1, 1); STAGE_A(1, 1, 1);
  asm volatile("s_waitcnt vmcnt(8)" ::: "memory");
  __builtin_amdgcn_s_barrier();

  #pragma unroll 1
  for (int ti = 0; ti < NT; ti += 2) {
    GROUP(ti, 0);
    GROUP(ti + 1, 1);
  }

#undef RD_A
#undef RD_B
#undef MFMAQ
#undef LGKM0
#undef GROUP
}

// ---------------- prep: 10 weight transposes + 4 LayerNorms, one dispatch ----------------
struct TDesc { const float* W; u16* WT; int K, N, tstart; };
struct PrepArgs {
  TDesc d[10];
  const float* lx[4]; const float* lg[4]; const float* lb_[4]; u16* lo[4];
  int ts;  // total transpose blocks
};
__global__ __launch_bounds__(256) void prep_kernel(PrepArgs P)
{
  __shared__ float sh[32*33];
  int tid = threadIdx.x;
  if ((int)blockIdx.x < P.ts) {
    int bi = blockIdx.x;
    int idx = 0;
    #pragma unroll
    for (int i = 1; i < 10; ++i) if (bi >= P.d[i].tstart) idx = i;
    const float* W = P.d[idx].W;
    u16* WT = P.d[idx].WT;
    int K = P.d[idx].K, N = P.d[idx].N;
    int loc = bi - P.d[idx].tstart;
    int tiles_n = N >> 5;
    int bn = loc % tiles_n, bk = loc / tiles_n;
    int tx = tid & 31, ty = tid >> 5;
    #pragma unroll
    for (int j = 0; j < 4; ++j)
      sh[(ty + j*8)*33 + tx] = W[(size_t)(bk*32 + ty + j*8) * N + bn*32 + tx];
    __syncthreads();
    #pragma unroll
    for (int j = 0; j < 4; ++j)
      WT[(size_t)(bn*32 + ty + j*8) * K + bk*32 + tx] = f2bf(sh[tx*33 + ty + j*8]);
  } else {
    int lid = blockIdx.x - P.ts;
    int id = lid >> 13, row = lid & 8191;
    const float4* xr = (const float4*)(P.lx[id] + (size_t)row * 1024);
    float4 v = xr[tid];
    float s = v.x + v.y + v.z + v.w;
    float ss = v.x*v.x + v.y*v.y + v.z*v.z + v.w*v.w;
    for (int d = 1; d < 64; d <<= 1) { s += __shfl_xor(s, d); ss += __shfl_xor(ss, d); }
    int wv = tid >> 6, lane = tid & 63;
    if (lane == 0) { sh[wv] = s; sh[4 + wv] = ss; }
    __syncthreads();
    s  = sh[0] + sh[1] + sh[2] + sh[3];
    ss = sh[4] + sh[5] + sh[6] + sh[7];
    float mean = s * (1.f/1024.f);
    float var  = ss * (1.f/1024.f) - mean*mean;
    float rs = rsqrtf(var + 1e-5f);
    float4 gv = ((const float4*)P.lg[id])[tid];
    float4 bv = ((const float4*)P.lb_[id])[tid];
    ushort4 o;
    o.x = f2bf((v.x-mean)*rs*gv.x + bv.x);
    o.y = f2bf((v.y-mean)*rs*gv.y + bv.y);
    o.z = f2bf((v.z-mean)*rs*gv.z + bv.z);
    o.w = f2bf((v.w-mean)*rs*gv.w + bv.w);
    ((ushort4*)P.lo[id])[(size_t)row*256 + tid] = o;
  }
}

// ---------------- LayerNorm with bf16 input: bf16 row -> bf16 row ----------------
__global__ __launch_bounds__(256) void ln_bf16_kernel(
    const u16* __restrict__ x, const float* __restrict__ g, const float* __restrict__ bt,
    u16* __restrict__ out)
{
  int row = blockIdx.x, tid = threadIdx.x;
  ushort4 xr = ((const ushort4*)x)[(size_t)row*256 + tid];
  float4 v;
  v.x = bf2f(xr.x); v.y = bf2f(xr.y); v.z = bf2f(xr.z); v.w = bf2f(xr.w);
  float s = v.x + v.y + v.z + v.w;
  float ss = v.x*v.x + v.y*v.y + v.z*v.z + v.w*v.w;
  for (int d = 1; d < 64; d <<= 1) { s += __shfl_xor(s, d); ss += __shfl_xor(ss, d); }
  __shared__ float red[8];
  int wv = tid >> 6, lane = tid & 63;
  if (lane == 0) { red[wv] = s; red[4 + wv] = ss; }
  __syncthreads();
  s  = red[0] + red[1] + red[2] + red[3];
  ss = red[4] + red[5] + red[6] + red[7];
  float mean = s * (1.f/1024.f);
  float var  = ss * (1.f/1024.f) - mean*mean;
  float rs = rsqrtf(var + 1e-5f);
  float4 gv = ((const float4*)g)[tid];
  float4 bv = ((const float4*)bt)[tid];
  ushort4 o;
  o.x = f2bf((v.x-mean)*rs*gv.x + bv.x);
  o.y = f2bf((v.y-mean)*rs*gv.y + bv.y);
  o.z = f2bf((v.z-mean)*rs*gv.z + bv.z);
  o.w = f2bf((v.w-mean)*rs*gv.w + bv.w);
  ((ushort4*)out)[(size_t)row*256 + tid] = o;
}

// ---------------- batched QKV GEMM (8-phase 256^2): 3 subs x 128 blocks ----------------
struct QkvArgs { const u16* A[3]; const u16* Bt[3]; u16* C[3]; };
__global__ __launch_bounds__(512, 2) void gemm8_qkv(QkvArgs P)
{
  __shared__ __align__(16) char lds8[131072];
  int sub = blockIdx.x >> 7;
  int local = blockIdx.x & 127;
  // XCD (local&7) owns a contiguous 4-row bm band; bn sweeps in lockstep
  int bm = (local & 7)*4 + ((local >> 3) & 3), bn = local >> 5;
  v4f acc[8][4] = {};
  gemm8_core<16>(P.A[sub], P.Bt[sub], lds8, bm, bn, threadIdx.x, acc);

  int tid = threadIdx.x, wid = tid >> 6, lane = tid & 63, quad = lane >> 4, lc = lane & 15;
  int wm = wid >> 2, wn = wid & 3;
  u16* Cout = P.C[sub];
  if (sub == 2) {
    #pragma unroll
    for (int mf = 0; mf < 8; ++mf) {
      int grow = bm*256 + wm*128 + mf*16 + quad*4;
      #pragma unroll
      for (int nf = 0; nf < 4; ++nf) {
        int gcol = bn*256 + wn*64 + nf*16 + lc;
        ushort4 o;
        o.x = f2bf(acc[mf][nf][0]); o.y = f2bf(acc[mf][nf][1]);
        o.z = f2bf(acc[mf][nf][2]); o.w = f2bf(acc[mf][nf][3]);
        *(ushort4*)(Cout + (size_t)gcol * 8192 + grow) = o;
      }
    }
  } else {
    // full-line stores via LDS round-trip (core done with LDS after its final barrier)
    #pragma unroll
    for (int mf = 0; mf < 8; ++mf) {
      int lrow = wm*128 + mf*16 + quad*4;
      #pragma unroll
      for (int nf = 0; nf < 4; ++nf) {
        int lcol = wn*64 + nf*16 + lc;
        #pragma unroll
        for (int i = 0; i < 4; ++i)
          *(u16*)(lds8 + (size_t)(lrow + i)*512 + (size_t)lcol*2) = f2bf(acc[mf][nf][i]);
      }
    }
    __syncthreads();
    int rr = tid >> 5, cseg = tid & 31;
    #pragma unroll
    for (int p = 0; p < 16; ++p) {
      int row = p*16 + rr;
      uint4 d = *(const uint4*)(lds8 + (size_t)row*512 + cseg*16);
      *(uint4*)(Cout + (size_t)(bm*256 + row)*1024 + bn*256 + cseg*8) = d;
    }
  }
}

// ---------------- Flash attention body (transposed-S formulation) ----------------
__device__ __forceinline__ void attn_body(
    const u16* __restrict__ Q, const u16* __restrict__ K, const u16* __restrict__ VT,
    u16* __restrict__ O, int bid, int tid, char* lds_)
{
  int qt = bid & 15, h = (bid >> 4) & 15, b = bid >> 8;
  int wv = tid >> 6, lane = tid & 63, quad = lane >> 4, lc = lane & 15;
  char* kt_l = lds_;            // K tile [128 kv][64 d], 128B rows, swizzled
  char* vt_l = lds_ + 16384;    // VT tile [64 d][128 kv], 256B rows, swizzled
  const float scale = 0.125f;

  v8bf qf[2];
  {
    int qrow = qt*64 + wv*16 + lc;
    const u16* qp = Q + ((size_t)(b*1024 + qrow) * 1024 + h*64 + quad*8);
    qf[0] = *(const v8bf*)qp;
    qf[1] = *(const v8bf*)(qp + 32);
  }

  float m_i = -1e30f, l_i = 0.f;
  v4f oacc[4] = {};

  for (int it = 0; it < 8; ++it) {
    int kvb = it * 128;
    __syncthreads();
    #pragma unroll
    for (int c0 = 0; c0 < 4; ++c0) {
      int ch = wv*4 + c0;
      int off = ch*1024 + lane*16;
      {
        int row = off >> 7, sc = (off >> 4) & 7, lg = sc ^ (row & 7);
        GLL16(K + (size_t)(b*1024 + kvb + row) * 1024 + h*64 + lg*8, kt_l + ch*1024);
      }
      {
        int row = off >> 8, sc = (off >> 4) & 15, lg = sc ^ (row & 15);
        GLL16(VT + (size_t)(h*64 + row) * 8192 + b*1024 + kvb + lg*8, vt_l + ch*1024);
      }
    }
    __syncthreads();

    v4f s[8] = {};
    #pragma unroll
    for (int ct = 0; ct < 8; ++ct) {
      int row = ct*16 + lc;
      #pragma unroll
      for (int kc = 0; kc < 2; ++kc) {
        int sc = (kc*4 + quad) ^ (row & 7);
        v8bf kf = *(const v8bf*)(kt_l + row*128 + sc*16);
        s[ct] = __builtin_amdgcn_mfma_f32_16x16x32_bf16(kf, qf[kc], s[ct], 0, 0, 0);
      }
    }

    float mx = m_i;
    #pragma unroll
    for (int ct = 0; ct < 8; ++ct)
      #pragma unroll
      for (int i = 0; i < 4; ++i) mx = fmaxf(mx, s[ct][i] * scale);
    mx = fmaxf(mx, __shfl_xor(mx, 16));
    mx = fmaxf(mx, __shfl_xor(mx, 32));
    float alpha = __expf(m_i - mx);
    float rs = 0.f;
    #pragma unroll
    for (int ct = 0; ct < 8; ++ct)
      #pragma unroll
      for (int i = 0; i < 4; ++i) {
        float p = __expf(s[ct][i] * scale - mx);
        s[ct][i] = p;
        rs += p;
      }
    rs += __shfl_xor(rs, 16);
    rs += __shfl_xor(rs, 32);
    l_i = l_i * alpha + rs;
    m_i = mx;
    #pragma unroll
    for (int dt = 0; dt < 4; ++dt)
      #pragma unroll
      for (int i = 0; i < 4; ++i) oacc[dt][i] *= alpha;

    #pragma unroll
    for (int ct = 0; ct < 8; ++ct) {
      v4s pfrag;
      #pragma unroll
      for (int i = 0; i < 4; ++i) pfrag[i] = (short)f2bf(s[ct][i]);
      int lg = ct*2 + (quad >> 1);
      int ho = (quad & 1) * 8;
      #pragma unroll
      for (int dt = 0; dt < 4; ++dt) {
        int rowd = dt*16 + lc;
        int sc = lg ^ (rowd & 15);
        v4s vfrag = *(const v4s*)(vt_l + rowd*256 + sc*16 + ho);
        oacc[dt] = __builtin_amdgcn_mfma_f32_16x16x16bf16_1k(vfrag, pfrag, oacc[dt], 0, 0, 0);
      }
    }
  }

  __syncthreads();
  {
    char* base = kt_l + wv*2048;
    float inv = 1.f / l_i;
    #pragma unroll
    for (int dt = 0; dt < 4; ++dt) {
      ushort4 o;
      o.x = f2bf(oacc[dt][0]*inv); o.y = f2bf(oacc[dt][1]*inv);
      o.z = f2bf(oacc[dt][2]*inv); o.w = f2bf(oacc[dt][3]*inv);
      int lg = dt*2 + (quad >> 1);
      int sc = lg ^ (lc & 7);
      *(ushort4*)(base + lc*128 + sc*16 + (quad & 1)*8) = o;
    }
  }
  __syncthreads();
  {
    char* base = kt_l + wv*2048;
    #pragma unroll
    for (int rep = 0; rep < 2; ++rep) {
      int qr = rep*8 + (lane >> 3);
      int ch = lane & 7;
      int sc = ch ^ (qr & 7);
      uint4 d = *(const uint4*)(base + qr*128 + sc*16);
      *(uint4*)(O + (size_t)(b*1024 + qt*64 + wv*16 + qr) * 1024 + h*64 + ch*8) = d;
    }
  }
}

// standalone attention
__global__ __launch_bounds__(256, 4) void attn_kernel(
    const u16* __restrict__ Q, const u16* __restrict__ K, const u16* __restrict__ VT,
    u16* __restrict__ O)
{
  __shared__ __align__(16) char lds_[32768];
  attn_body(Q, K, VT, O, blockIdx.x, threadIdx.x, lds_);
}

// ---------------- fused attention-2 || proj-1 (bias + bf16 out) ----------------
__global__ __launch_bounds__(256, 3) void attn_proj_kernel(
    const u16* __restrict__ Q, const u16* __restrict__ K, const u16* __restrict__ VT,
    u16* __restrict__ O,
    const u16* __restrict__ GA, const u16* __restrict__ GBt,
    const float* __restrict__ Gbias, u16* __restrict__ GC)
{
  __shared__ __align__(16) char lds_[32768];
  int tid = threadIdx.x;
  if ((int)blockIdx.x < 2048) {
    attn_body(Q, K, VT, O, blockIdx.x, tid, lds_);
  } else {
    int local = blockIdx.x - 2048;
    TILE_MAP(local, bm, bn)
    int wv = tid >> 6, lane = tid & 63, quad = lane >> 4, lc = lane & 15;
    int wm = wv & 1, wn = wv >> 1;
    v4f acc[4][4] = {};
    gemm_core(GA, GBt, 1024, lds_, lds_ + 16384, bm, bn, tid, acc);
    #pragma unroll
    for (int r = 0; r < 4; ++r) {
      int grow = bm*128 + wm*64 + r*16 + quad*4;
      #pragma unroll
      for (int c = 0; c < 4; ++c) {
        int gcol = bn*128 + wn*64 + c*16 + lc;
        float bv = Gbias[gcol];
        #pragma unroll
        for (int i = 0; i < 4; ++i)
          GC[(size_t)(grow + i) * 1024 + gcol] = f2bf(acc[r][c][i] + bv);
      }
    }
  }
}

// ---------------- proj-2 + residual sum: xsum(bf16) = O2@wp2 + bp2 + x1 + o1 ----------------
__global__ __launch_bounds__(256, 3) void gemm_projadd(
    const u16* __restrict__ A, const u16* __restrict__ Bt,
    const float* __restrict__ bias, const float* __restrict__ x1,
    const u16* __restrict__ o1b, u16* __restrict__ xsum)
{
  TILE_MAP((int)blockIdx.x, bm, bn)
  int tid = threadIdx.x, wv = tid >> 6, lane = tid & 63, quad = lane >> 4, lc = lane & 15;
  int wm = wv & 1, wn = wv >> 1;
  __shared__ __align__(16) char lds_[32768];
  v4f acc[4][4] = {};
  gemm_core(A, Bt, 1024, lds_, lds_ + 16384, bm, bn, tid, acc);
  #pragma unroll
  for (int r = 0; r < 4; ++r) {
    int grow = bm*128 + wm*64 + r*16 + quad*4;
    #pragma unroll
    for (int c = 0; c < 4; ++c) {
      int gcol = bn*128 + wn*64 + c*16 + lc;
      float bv = bias[gcol];
      #pragma unroll
      for (int i = 0; i < 4; ++i) {
        size_t idx = (size_t)(grow + i) * 1024 + gcol;
        xsum[idx] = f2bf(acc[r][c][i] + bv + x1[idx] + bf2f(o1b[idx]));
      }
    }
  }
}

// ---------------- fc1: 8-phase 256^2, bias + fast GELU, bf16 out, N=4096 ----------------
__global__ __launch_bounds__(512, 2) void gemm_fc1(
    const u16* __restrict__ A, const u16* __restrict__ Bt,
    const float* __restrict__ bias, u16* __restrict__ C)
{
  __shared__ __align__(16) char lds8[131072];
  int blk = blockIdx.x;
  int bm = (blk & 7)*4 + ((blk >> 3) & 3), bn = blk >> 5;   // 32 x 16 tiles
  v4f acc[8][4] = {};
  gemm8_core<16>(A, Bt, lds8, bm, bn, threadIdx.x, acc);

  int tid = threadIdx.x, wid = tid >> 6, lane = tid & 63, quad = lane >> 4, lc = lane & 15;
  int wm = wid >> 2, wn = wid & 3;
  // bias + GELU into LDS, then full-line global stores
  #pragma unroll
  for (int nf = 0; nf < 4; ++nf) {
    int lcol = wn*64 + nf*16 + lc;
    float bv = bias[bn*256 + lcol];
    #pragma unroll
    for (int mf = 0; mf < 8; ++mf) {
      int lrow = wm*128 + mf*16 + quad*4;
      #pragma unroll
      for (int i = 0; i < 4; ++i) {
        float v = acc[mf][nf][i] + bv;
        // tanh-form GELU via hardware exp: gelu = v * t/(t+1), t = e^{2*0.79788456*(v+0.044715 v^3)}
        float u2 = fminf(1.5957691216f * (v + 0.044715f * v * v * v), 80.f);
        float t = __expf(u2);
        *(u16*)(lds8 + (size_t)(lrow + i)*512 + (size_t)lcol*2) = f2bf(v * t / (t + 1.f));
      }
    }
  }
  __syncthreads();
  int rr = tid >> 5, cseg = tid & 31;
  #pragma unroll
  for (int p = 0; p < 16; ++p) {
    int row = p*16 + rr;
    uint4 d = *(const uint4*)(lds8 + (size_t)row*512 + cseg*16);
    *(uint4*)(C + (size_t)(bm*256 + row)*4096 + bn*256 + cseg*8) = d;
  }
}

// ---------------- fc2: bias + residual(bf16), fp32 out, K=4096 ----------------
__global__ __launch_bounds__(256, 3) void gemm_fc2(
    const u16* __restrict__ A, const u16* __restrict__ Bt,
    const float* __restrict__ bias, const u16* __restrict__ r1,
    float* __restrict__ C)
{
  TILE_MAP((int)blockIdx.x, bm, bn)
  int tid = threadIdx.x, wv = tid >> 6, lane = tid & 63, quad = lane >> 4, lc = lane & 15;
  int wm = wv & 1, wn = wv >> 1;
  __shared__ __align__(16) char lds_[32768];
  v4f acc[4][4] = {};
  gemm_core(A, Bt, 4096, lds_, lds_ + 16384, bm, bn, tid, acc);
  #pragma unroll
  for (int r = 0; r < 4; ++r) {
    int grow = bm*128 + wm*64 + r*16 + quad*4;
    #pragma unroll
    for (int c = 0; c < 4; ++c) {
      int gcol = bn*128 + wn*64 + c*16 + lc;
      float bv = bias[gcol];
      #pragma unroll
      for (int i = 0; i < 4; ++i) {
        size_t idx = (size_t)(grow + i) * 1024 + gcol;
        C[idx] = acc[r][c][i] + bv + bf2f(r1[idx]);
      }
    }
  }
}

// ---------------- host ----------------
extern "C" void kernel_launch(void* const* d_in, const int* in_sizes, int n_in,
                              void* d_out, int out_size, void* d_ws, size_t ws_size,
                              hipStream_t stream)
{
  const float* x1    = (const float*)d_in[0];
  const float* x2    = (const float*)d_in[1];
  const float* x3    = (const float*)d_in[2];
  const float* ln11g = (const float*)d_in[3];
  const float* ln11b = (const float*)d_in[4];
  const float* ln12g = (const float*)d_in[5];
  const float* ln12b = (const float*)d_in[6];
  const float* ln21g = (const float*)d_in[7];
  const float* ln21b = (const float*)d_in[8];
  const float* ln23g = (const float*)d_in[9];
  const float* ln23b = (const float*)d_in[10];
  const float* ln2g  = (const float*)d_in[11];
  const float* ln2b  = (const float*)d_in[12];
  const float* a1wq  = (const float*)d_in[13];
  const float* a1wk  = (const float*)d_in[14];
  const float* a1wv  = (const float*)d_in[15];
  const float* a1wp  = (const float*)d_in[16];
  const float* a1bp  = (const float*)d_in[17];
  const float* a2wq  = (const float*)d_in[18];
  const float* a2wk  = (const float*)d_in[19];
  const float* a2wv  = (const float*)d_in[20];
  const float* a2wp  = (const float*)d_in[21];
  const float* a2bp  = (const float*)d_in[22];
  const float* fc1w  = (const float*)d_in[23];
  const float* fc1b  = (const float*)d_in[24];
  const float* fc2w  = (const float*)d_in[25];
  const float* fc2b  = (const float*)d_in[26];

  char* ws = (char*)d_ws;
  const size_t MB = (size_t)1 << 20;
  // weights (persistent, 0-32 MB)
  u16* wtq1 = (u16*)(ws + 0*MB);  u16* wtk1 = (u16*)(ws + 2*MB);
  u16* wtv1 = (u16*)(ws + 4*MB);  u16* wtp1 = (u16*)(ws + 6*MB);
  u16* wtq2 = (u16*)(ws + 8*MB);  u16* wtk2 = (u16*)(ws + 10*MB);
  u16* wtv2 = (u16*)(ws + 12*MB); u16* wtp2 = (u16*)(ws + 14*MB);
  u16* wtf1 = (u16*)(ws + 16*MB); u16* wtf2 = (u16*)(ws + 24*MB);
  // activations (liveness-overlapped; peak 144 MB)
  u16* xq1  = (u16*)(ws + 32*MB); u16* xkv1 = (u16*)(ws + 48*MB);
  u16* xq2  = (u16*)(ws + 64*MB); u16* xkv2 = (u16*)(ws + 80*MB);
  u16* Qb   = (u16*)(ws + 96*MB); u16* Kb   = (u16*)(ws + 112*MB);
  u16* VTb  = (u16*)(ws + 128*MB);
  u16* O1   = (u16*)(ws + 32*MB);                 // over xq1 (dead after g1)
  u16* O2   = (u16*)(ws + 48*MB);                 // over xkv1 (dead after g1)
  u16* o1b  = (u16*)(ws + 64*MB);                 // over xq2 (dead after g2), bf16
  u16* xsum = (u16*)(ws + 112*MB);                // bf16, over Kb (dead after attn2)
  u16* ln2o = (u16*)(ws + 32*MB);                 // over O1 (dead after proj1)
  u16* hbuf = (u16*)(ws + 48*MB);                 // 48-112 (all dead by fc1)

  dim3 blk(256);
  dim3 blk8(512);

  // D0: all weight transposes + 4 LNs
  PrepArgs pa;
  const float* Ws[10]  = {a1wq, a1wk, a1wv, a1wp, a2wq, a2wk, a2wv, a2wp, fc1w, fc2w};
  u16* WTs[10]         = {wtq1, wtk1, wtv1, wtp1, wtq2, wtk2, wtv2, wtp2, wtf1, wtf2};
  int Kd[10] = {1024,1024,1024,1024,1024,1024,1024,1024,1024,4096};
  int Nd[10] = {1024,1024,1024,1024,1024,1024,1024,1024,4096,1024};
  int ts = 0;
  for (int i = 0; i < 10; ++i) {
    pa.d[i] = {Ws[i], WTs[i], Kd[i], Nd[i], ts};
    ts += (Kd[i]/32) * (Nd[i]/32);
  }
  pa.ts = ts;   // 16384
  pa.lx[0]=x1; pa.lg[0]=ln11g; pa.lb_[0]=ln11b; pa.lo[0]=xq1;
  pa.lx[1]=x2; pa.lg[1]=ln12g; pa.lb_[1]=ln12b; pa.lo[1]=xkv1;
  pa.lx[2]=x1; pa.lg[2]=ln21g; pa.lb_[2]=ln21b; pa.lo[2]=xq2;
  pa.lx[3]=x3; pa.lg[3]=ln23g; pa.lb_[3]=ln23b; pa.lo[3]=xkv2;
  prep_kernel<<<ts + 32768, blk, 0, stream>>>(pa);

  // D1: branch-1 Q/K/VT (8-phase 256^2 core)
  QkvArgs g1;
  g1.A[0]=xq1;  g1.Bt[0]=wtq1; g1.C[0]=Qb;
  g1.A[1]=xkv1; g1.Bt[1]=wtk1; g1.C[1]=Kb;
  g1.A[2]=xkv1; g1.Bt[2]=wtv1; g1.C[2]=VTb;
  gemm8_qkv<<<384, blk8, 0, stream>>>(g1);

  // D2: attention 1
  attn_kernel<<<2048, blk, 0, stream>>>(Qb, Kb, VTb, O1);

  // D3: branch-2 Q/K/VT (reuses Qb/Kb/VTb)
  QkvArgs g2;
  g2.A[0]=xq2;  g2.Bt[0]=wtq2; g2.C[0]=Qb;
  g2.A[1]=xkv2; g2.Bt[1]=wtk2; g2.C[1]=Kb;
  g2.A[2]=xkv2; g2.Bt[2]=wtv2; g2.C[2]=VTb;
  gemm8_qkv<<<384, blk8, 0, stream>>>(g2);

  // D4: attention 2  ||  proj-1 (o1 = O1@wp1 + bp1, bf16)
  attn_proj_kernel<<<2048 + 512, blk, 0, stream>>>(Qb, Kb, VTb, O2, O1, wtp1, a1bp, o1b);

  // D5: proj-2 + residual sum -> xsum (bf16)
  gemm_projadd<<<512, blk, 0, stream>>>(O2, wtp2, a2bp, x1, o1b, xsum);

  // D6: LN2 -> bf16
  ln_bf16_kernel<<<8192, blk, 0, stream>>>(xsum, ln2g, ln2b, ln2o);

  // D7: fc1 + GELU (8-phase 256^2 core)
  gemm_fc1<<<512, blk8, 0, stream>>>(ln2o, wtf1, fc1b, hbuf);

  // D8: fc2 + bias + residual -> d_out (fp32)
  gemm_fc2<<<512, blk, 0, stream>>>(hbuf, wtf2, fc2b, xsum, (float*)d_out);
}

// Round 3
// 693.452 us; speedup vs baseline: 1.0279x; 1.0279x over previous
//
#include <hip/hip_runtime.h>
#include <hip/hip_bf16.h>
#include <cstdint>

typedef unsigned short u16;
typedef __bf16 v8bf __attribute__((ext_vector_type(8)));
typedef short v4s __attribute__((ext_vector_type(4)));
typedef float v4f __attribute__((ext_vector_type(4)));

__device__ __forceinline__ u16 f2bf(float f) {
  union { float f; uint32_t u; } v; v.f = f;
  return (u16)((v.u + 0x7fffu + ((v.u >> 16) & 1u)) >> 16);
}
__device__ __forceinline__ float bf2f(u16 u) {
  union { uint32_t u; float f; } v; v.u = ((uint32_t)u) << 16; return v.f;
}
// hardware 2^x (v_exp_f32); args <= 0 underflow to 0, large args fine in fp32
__device__ __forceinline__ float ex2(float x) {
  float r; asm("v_exp_f32 %0, %1" : "=v"(r) : "v"(x)); return r;
}

// async global->LDS, 16B per lane; LDS dest = wave-uniform base + lane*16
#define GLL16(gsrc, ldst) \
  __builtin_amdgcn_global_load_lds((__attribute__((address_space(1))) void*)(gsrc), \
      (__attribute__((address_space(3))) void*)(ldst), 16, 0, 0)

// XCD-aware tile map (64 bm-tiles, M=8192): XCD (blk%8) owns a contiguous
// 8-row bm band; co-resident blocks sweep bn in lockstep.
#define TILE_MAP(blk, bm, bn) \
  int bm = ((blk) & 7) * 8 + (((blk) >> 3) & 7); \
  int bn = (blk) >> 6;

// ---------------- GEMM core (128x128 tile, BK=64, XOR-swizzled LDS) ----------------
__device__ __forceinline__ void gemm_core(
    const u16* __restrict__ A, const u16* __restrict__ Bt, int K,
    char* la, char* lb, int bm, int bn, int tid, v4f acc[4][4])
{
  int wv = tid >> 6, lane = tid & 63, quad = lane >> 4, lc = lane & 15;
  int wm = wv & 1, wn = wv >> 1;
  for (int kt = 0; kt < K; kt += 64) {
    __syncthreads();
    #pragma unroll
    for (int c0 = 0; c0 < 4; ++c0) {
      int chunk = wv*4 + c0;
      int off = chunk*1024 + lane*16;
      int row = off >> 7;
      int sc  = (off >> 4) & 7;
      int lg  = sc ^ (row & 7);
      GLL16(A  + (size_t)(bm*128 + row) * K + kt + lg*8, la + chunk*1024);
      GLL16(Bt + (size_t)(bn*128 + row) * K + kt + lg*8, lb + chunk*1024);
    }
    __syncthreads();
    #pragma unroll
    for (int kc = 0; kc < 2; ++kc) {
      v8bf af[4], bfr[4];
      #pragma unroll
      for (int r = 0; r < 4; ++r) {
        int row = wm*64 + r*16 + lc;
        int sc = (kc*4 + quad) ^ (row & 7);
        af[r] = *(const v8bf*)(la + row*128 + sc*16);
      }
      #pragma unroll
      for (int c = 0; c < 4; ++c) {
        int row = wn*64 + c*16 + lc;
        int sc = (kc*4 + quad) ^ (row & 7);
        bfr[c] = *(const v8bf*)(lb + row*128 + sc*16);
      }
      #pragma unroll
      for (int r = 0; r < 4; ++r)
        #pragma unroll
        for (int c = 0; c < 4; ++c)
          acc[r][c] = __builtin_amdgcn_mfma_f32_16x16x32_bf16(af[r], bfr[c], acc[r][c], 0, 0, 0);
    }
  }
}

// ---------------- epilogue: swizzled 128x128 bf16 LDS tile + full-line stores ----------------
// physical 32B chunk = logical chunk ^ (row&7): write conflicts ~2-way (free)
__device__ __forceinline__ void lds_put16(char* lds_, int row, int col, u16 v) {
  *(u16*)(lds_ + row*256 + (((col >> 4) ^ (row & 7)) << 5) + (col & 15)*2) = v;
}
// 256 threads sweep 128 rows x 256B; each global store inst covers 256B (2 lines)
__device__ __forceinline__ void sweep128(const char* lds_, u16* gout, size_t ldc, int tid) {
  int sub = tid >> 4, j = tid & 15;
  #pragma unroll
  for (int p = 0; p < 8; ++p) {
    int row = p*16 + sub;
    uint4 d = *(const uint4*)(lds_ + row*256 + ((((j >> 1) ^ (row & 7)) << 5) + ((j & 1) << 4)));
    *(uint4*)(gout + (size_t)row*ldc + j*8) = d;
  }
}

// ---------------- prep helpers ----------------
struct TDesc { const float* W; u16* WT; int K, N, tstart; };

__device__ __forceinline__ void do_transpose(const TDesc& D, int loc, int tid, float* sh) {
  const float* W = D.W;
  u16* WT = D.WT;
  int K = D.K, N = D.N;
  int tiles_n = N >> 5;
  int bn = loc % tiles_n, bk = loc / tiles_n;
  int tx = tid & 31, ty = tid >> 5;
  #pragma unroll
  for (int j = 0; j < 4; ++j)
    sh[(ty + j*8)*33 + tx] = W[(size_t)(bk*32 + ty + j*8) * N + bn*32 + tx];
  __syncthreads();
  #pragma unroll
  for (int j = 0; j < 4; ++j)
    WT[(size_t)(bn*32 + ty + j*8) * K + bk*32 + tx] = f2bf(sh[tx*33 + ty + j*8]);
}

// fp32 row LN -> one bf16 output
__device__ __forceinline__ void ln_f32_row(const float* x, const float* g, const float* b,
                                           u16* out, int row, int tid, float* red)
{
  float4 v = ((const float4*)(x + (size_t)row * 1024))[tid];
  float s = v.x + v.y + v.z + v.w;
  float ss = v.x*v.x + v.y*v.y + v.z*v.z + v.w*v.w;
  for (int d = 1; d < 64; d <<= 1) { s += __shfl_xor(s, d); ss += __shfl_xor(ss, d); }
  int wv = tid >> 6, lane = tid & 63;
  if (lane == 0) { red[wv] = s; red[4 + wv] = ss; }
  __syncthreads();
  s  = red[0] + red[1] + red[2] + red[3];
  ss = red[4] + red[5] + red[6] + red[7];
  float mean = s * (1.f/1024.f);
  float var  = ss * (1.f/1024.f) - mean*mean;
  float rs = rsqrtf(var + 1e-5f);
  float4 gv = ((const float4*)g)[tid];
  float4 bv = ((const float4*)b)[tid];
  ushort4 o;
  o.x = f2bf((v.x-mean)*rs*gv.x + bv.x);
  o.y = f2bf((v.y-mean)*rs*gv.y + bv.y);
  o.z = f2bf((v.z-mean)*rs*gv.z + bv.z);
  o.w = f2bf((v.w-mean)*rs*gv.w + bv.w);
  ((ushort4*)out)[(size_t)row*256 + tid] = o;
}

// fp32 row LN -> TWO bf16 outputs (shared mean/var, distinct gamma/beta)
__device__ __forceinline__ void ln_f32_row2(const float* x,
    const float* g1, const float* b1, const float* g2, const float* b2,
    u16* o1, u16* o2, int row, int tid, float* red)
{
  float4 v = ((const float4*)(x + (size_t)row * 1024))[tid];
  float s = v.x + v.y + v.z + v.w;
  float ss = v.x*v.x + v.y*v.y + v.z*v.z + v.w*v.w;
  for (int d = 1; d < 64; d <<= 1) { s += __shfl_xor(s, d); ss += __shfl_xor(ss, d); }
  int wv = tid >> 6, lane = tid & 63;
  if (lane == 0) { red[wv] = s; red[4 + wv] = ss; }
  __syncthreads();
  s  = red[0] + red[1] + red[2] + red[3];
  ss = red[4] + red[5] + red[6] + red[7];
  float mean = s * (1.f/1024.f);
  float var  = ss * (1.f/1024.f) - mean*mean;
  float rs = rsqrtf(var + 1e-5f);
  float4 xn;
  xn.x = (v.x-mean)*rs; xn.y = (v.y-mean)*rs; xn.z = (v.z-mean)*rs; xn.w = (v.w-mean)*rs;
  {
    float4 gv = ((const float4*)g1)[tid];
    float4 bv = ((const float4*)b1)[tid];
    ushort4 o;
    o.x = f2bf(xn.x*gv.x + bv.x); o.y = f2bf(xn.y*gv.y + bv.y);
    o.z = f2bf(xn.z*gv.z + bv.z); o.w = f2bf(xn.w*gv.w + bv.w);
    ((ushort4*)o1)[(size_t)row*256 + tid] = o;
  }
  {
    float4 gv = ((const float4*)g2)[tid];
    float4 bv = ((const float4*)b2)[tid];
    ushort4 o;
    o.x = f2bf(xn.x*gv.x + bv.x); o.y = f2bf(xn.y*gv.y + bv.y);
    o.z = f2bf(xn.z*gv.z + bv.z); o.w = f2bf(xn.w*gv.w + bv.w);
    ((ushort4*)o2)[(size_t)row*256 + tid] = o;
  }
}

// ---------------- prep A: qkv1 prerequisites only ----------------
// blocks [0, tsa): transposes of wq1/wk1/wv1; then 8192 dual-LN(x1) + 8192 LN(x2)
struct PrepA {
  TDesc d[3];
  const float *x1, *g11, *b11, *g21, *b21;
  const float *x2, *g12, *b12;
  u16 *xq1, *xq2, *xkv1;
  int tsa;
};
__global__ __launch_bounds__(256) void prep_a_kernel(PrepA P)
{
  __shared__ float sh[32*33];
  int tid = threadIdx.x;
  int bi = blockIdx.x;
  if (bi < P.tsa) {
    int idx = 0;
    #pragma unroll
    for (int i = 1; i < 3; ++i) if (bi >= P.d[i].tstart) idx = i;
    do_transpose(P.d[idx], bi - P.d[idx].tstart, tid, sh);
  } else {
    int lid = bi - P.tsa;
    if (lid < 8192)
      ln_f32_row2(P.x1, P.g11, P.b11, P.g21, P.b21, P.xq1, P.xq2, lid, tid, sh);
    else
      ln_f32_row(P.x2, P.g12, P.b12, P.xkv1, lid - 8192, tid, sh);
  }
}

// ---------------- LayerNorm with bf16 input: bf16 row -> bf16 row ----------------
__global__ __launch_bounds__(256) void ln_bf16_kernel(
    const u16* __restrict__ x, const float* __restrict__ g, const float* __restrict__ bt,
    u16* __restrict__ out)
{
  int row = blockIdx.x, tid = threadIdx.x;
  ushort4 xr = ((const ushort4*)x)[(size_t)row*256 + tid];
  float4 v;
  v.x = bf2f(xr.x); v.y = bf2f(xr.y); v.z = bf2f(xr.z); v.w = bf2f(xr.w);
  float s = v.x + v.y + v.z + v.w;
  float ss = v.x*v.x + v.y*v.y + v.z*v.z + v.w*v.w;
  for (int d = 1; d < 64; d <<= 1) { s += __shfl_xor(s, d); ss += __shfl_xor(ss, d); }
  __shared__ float red[8];
  int wv = tid >> 6, lane = tid & 63;
  if (lane == 0) { red[wv] = s; red[4 + wv] = ss; }
  __syncthreads();
  s  = red[0] + red[1] + red[2] + red[3];
  ss = red[4] + red[5] + red[6] + red[7];
  float mean = s * (1.f/1024.f);
  float var  = ss * (1.f/1024.f) - mean*mean;
  float rs = rsqrtf(var + 1e-5f);
  float4 gv = ((const float4*)g)[tid];
  float4 bv = ((const float4*)bt)[tid];
  ushort4 o;
  o.x = f2bf((v.x-mean)*rs*gv.x + bv.x);
  o.y = f2bf((v.y-mean)*rs*gv.y + bv.y);
  o.z = f2bf((v.z-mean)*rs*gv.z + bv.z);
  o.w = f2bf((v.w-mean)*rs*gv.w + bv.w);
  ((ushort4*)out)[(size_t)row*256 + tid] = o;
}

// ---------------- QKV GEMM body (3 subs x 512 tiles) with full-line epilogues ----------------
struct QkvArgs { const u16* A[3]; const u16* Bt[3]; u16* C[3]; };

__device__ __forceinline__ void qkv_body(const QkvArgs& P, int blk, int tid, char* lds_)
{
  int sub = blk >> 9;
  int local = blk & 511;
  TILE_MAP(local, bm, bn)
  int wv = tid >> 6, lane = tid & 63, quad = lane >> 4, lc = lane & 15;
  int wm = wv & 1, wn = wv >> 1;
  v4f acc[4][4] = {};
  gemm_core(P.A[sub], P.Bt[sub], 1024, lds_, lds_ + 16384, bm, bn, tid, acc);
  u16* Cout = P.C[sub];
  __syncthreads();
  if (sub == 2) {
    // VT: transposed tile in LDS (lds row = d-col), rows stream 256B into VT
    #pragma unroll
    for (int r = 0; r < 4; ++r) {
      int rl = wm*64 + r*16 + quad*4;
      #pragma unroll
      for (int c = 0; c < 4; ++c) {
        int cl = wn*64 + c*16 + lc;
        #pragma unroll
        for (int i = 0; i < 4; ++i)
          lds_put16(lds_, cl, rl + i, f2bf(acc[r][c][i]));
      }
    }
    __syncthreads();
    sweep128(lds_, Cout + (size_t)(bn*128) * 8192 + bm*128, 8192, tid);
  } else {
    #pragma unroll
    for (int r = 0; r < 4; ++r) {
      int lrow = wm*64 + r*16 + quad*4;
      #pragma unroll
      for (int c = 0; c < 4; ++c) {
        int lcol = wn*64 + c*16 + lc;
        #pragma unroll
        for (int i = 0; i < 4; ++i)
          lds_put16(lds_, lrow + i, lcol, f2bf(acc[r][c][i]));
      }
    }
    __syncthreads();
    sweep128(lds_, Cout + (size_t)(bm*128) * 1024 + bn*128, 1024, tid);
  }
}

__global__ __launch_bounds__(256, 3) void gemm_qkv(QkvArgs P)
{
  __shared__ __align__(16) char lds_[32768];
  qkv_body(P, blockIdx.x, threadIdx.x, lds_);
}

// ---------------- fused: qkv1 (1536 blocks) || remaining prep (7 transposes + LN x3) ----------------
struct PrepB {
  TDesc d[7];
  const float *x3, *g23, *b23;
  u16 *xkv2;
  int tsb;
};
__global__ __launch_bounds__(256, 3) void qkv_prep_kernel(QkvArgs P, PrepB Q)
{
  __shared__ __align__(16) char lds_[32768];
  int tid = threadIdx.x;
  if ((int)blockIdx.x < 1536) {
    qkv_body(P, blockIdx.x, tid, lds_);
  } else {
    float* sh = (float*)lds_;
    int bi = blockIdx.x - 1536;
    if (bi < Q.tsb) {
      int idx = 0;
      #pragma unroll
      for (int i = 1; i < 7; ++i) if (bi >= Q.d[i].tstart) idx = i;
      do_transpose(Q.d[idx], bi - Q.d[idx].tstart, tid, sh);
    } else {
      ln_f32_row(Q.x3, Q.g23, Q.b23, Q.xkv2, bi - Q.tsb, tid, sh);
    }
  }
}

// ---------------- Flash attention body (transposed-S, exp2-domain softmax) ----------------
__device__ __forceinline__ void attn_body(
    const u16* __restrict__ Q, const u16* __restrict__ K, const u16* __restrict__ VT,
    u16* __restrict__ O, int bid, int tid, char* lds_)
{
  int qt = bid & 15, h = (bid >> 4) & 15, b = bid >> 8;
  int wv = tid >> 6, lane = tid & 63, quad = lane >> 4, lc = lane & 15;
  char* kt_l = lds_;            // K tile [128 kv][64 d], 128B rows, swizzled
  char* vt_l = lds_ + 16384;    // VT tile [64 d][128 kv], 256B rows, swizzled
  const float cl2 = 0.18033688f;   // 0.125 * log2(e): softmax in exp2 domain

  v8bf qf[2];
  {
    int qrow = qt*64 + wv*16 + lc;
    const u16* qp = Q + ((size_t)(b*1024 + qrow) * 1024 + h*64 + quad*8);
    qf[0] = *(const v8bf*)qp;
    qf[1] = *(const v8bf*)(qp + 32);
  }

  float m_i = -1e30f, l_i = 0.f;
  v4f oacc[4] = {};

  for (int it = 0; it < 8; ++it) {
    int kvb = it * 128;
    __syncthreads();
    #pragma unroll
    for (int c0 = 0; c0 < 4; ++c0) {
      int ch = wv*4 + c0;
      int off = ch*1024 + lane*16;
      {
        int row = off >> 7, sc = (off >> 4) & 7, lg = sc ^ (row & 7);
        GLL16(K + (size_t)(b*1024 + kvb + row) * 1024 + h*64 + lg*8, kt_l + ch*1024);
      }
      {
        int row = off >> 8, sc = (off >> 4) & 15, lg = sc ^ (row & 15);
        GLL16(VT + (size_t)(h*64 + row) * 8192 + b*1024 + kvb + lg*8, vt_l + ch*1024);
      }
    }
    __syncthreads();

    v4f s[8] = {};
    #pragma unroll
    for (int ct = 0; ct < 8; ++ct) {
      int row = ct*16 + lc;
      #pragma unroll
      for (int kc = 0; kc < 2; ++kc) {
        int sc = (kc*4 + quad) ^ (row & 7);
        v8bf kf = *(const v8bf*)(kt_l + row*128 + sc*16);
        s[ct] = __builtin_amdgcn_mfma_f32_16x16x32_bf16(kf, qf[kc], s[ct], 0, 0, 0);
      }
    }

    // prescale into exp2 domain once
    #pragma unroll
    for (int ct = 0; ct < 8; ++ct)
      #pragma unroll
      for (int i = 0; i < 4; ++i) s[ct][i] *= cl2;
    float mx = m_i;
    #pragma unroll
    for (int ct = 0; ct < 8; ++ct)
      #pragma unroll
      for (int i = 0; i < 4; ++i) mx = fmaxf(mx, s[ct][i]);
    mx = fmaxf(mx, __shfl_xor(mx, 16));
    mx = fmaxf(mx, __shfl_xor(mx, 32));
    float alpha = ex2(m_i - mx);
    float rs = 0.f;
    #pragma unroll
    for (int ct = 0; ct < 8; ++ct)
      #pragma unroll
      for (int i = 0; i < 4; ++i) {
        float p = ex2(s[ct][i] - mx);
        s[ct][i] = p;
        rs += p;
      }
    rs += __shfl_xor(rs, 16);
    rs += __shfl_xor(rs, 32);
    l_i = l_i * alpha + rs;
    m_i = mx;
    #pragma unroll
    for (int dt = 0; dt < 4; ++dt)
      #pragma unroll
      for (int i = 0; i < 4; ++i) oacc[dt][i] *= alpha;

    #pragma unroll
    for (int ct = 0; ct < 8; ++ct) {
      v4s pfrag;
      #pragma unroll
      for (int i = 0; i < 4; ++i) pfrag[i] = (short)f2bf(s[ct][i]);
      int lg = ct*2 + (quad >> 1);
      int ho = (quad & 1) * 8;
      #pragma unroll
      for (int dt = 0; dt < 4; ++dt) {
        int rowd = dt*16 + lc;
        int sc = lg ^ (rowd & 15);
        v4s vfrag = *(const v4s*)(vt_l + rowd*256 + sc*16 + ho);
        oacc[dt] = __builtin_amdgcn_mfma_f32_16x16x16bf16_1k(vfrag, pfrag, oacc[dt], 0, 0, 0);
      }
    }
  }

  __syncthreads();
  {
    char* base = kt_l + wv*2048;
    float inv = 1.f / l_i;
    #pragma unroll
    for (int dt = 0; dt < 4; ++dt) {
      ushort4 o;
      o.x = f2bf(oacc[dt][0]*inv); o.y = f2bf(oacc[dt][1]*inv);
      o.z = f2bf(oacc[dt][2]*inv); o.w = f2bf(oacc[dt][3]*inv);
      int lg = dt*2 + (quad >> 1);
      int sc = lg ^ (lc & 7);
      *(ushort4*)(base + lc*128 + sc*16 + (quad & 1)*8) = o;
    }
  }
  __syncthreads();
  {
    char* base = kt_l + wv*2048;
    #pragma unroll
    for (int rep = 0; rep < 2; ++rep) {
      int qr = rep*8 + (lane >> 3);
      int ch = lane & 7;
      int sc = ch ^ (qr & 7);
      uint4 d = *(const uint4*)(base + qr*128 + sc*16);
      *(uint4*)(O + (size_t)(b*1024 + qt*64 + wv*16 + qr) * 1024 + h*64 + ch*8) = d;
    }
  }
}

// standalone attention
__global__ __launch_bounds__(256, 4) void attn_kernel(
    const u16* __restrict__ Q, const u16* __restrict__ K, const u16* __restrict__ VT,
    u16* __restrict__ O)
{
  __shared__ __align__(16) char lds_[32768];
  attn_body(Q, K, VT, O, blockIdx.x, threadIdx.x, lds_);
}

// ---------------- fused attention-2 || proj-1 (bias + bf16 out, full-line stores) ----------------
__global__ __launch_bounds__(256, 3) void attn_proj_kernel(
    const u16* __restrict__ Q, const u16* __restrict__ K, const u16* __restrict__ VT,
    u16* __restrict__ O,
    const u16* __restrict__ GA, const u16* __restrict__ GBt,
    const float* __restrict__ Gbias, u16* __restrict__ GC)
{
  __shared__ __align__(16) char lds_[32768];
  int tid = threadIdx.x;
  if ((int)blockIdx.x < 2048) {
    attn_body(Q, K, VT, O, blockIdx.x, tid, lds_);
  } else {
    int local = blockIdx.x - 2048;
    TILE_MAP(local, bm, bn)
    int wv = tid >> 6, lane = tid & 63, quad = lane >> 4, lc = lane & 15;
    int wm = wv & 1, wn = wv >> 1;
    v4f acc[4][4] = {};
    gemm_core(GA, GBt, 1024, lds_, lds_ + 16384, bm, bn, tid, acc);
    __syncthreads();
    #pragma unroll
    for (int r = 0; r < 4; ++r) {
      int lrow = wm*64 + r*16 + quad*4;
      #pragma unroll
      for (int c = 0; c < 4; ++c) {
        int lcol = wn*64 + c*16 + lc;
        float bv = Gbias[bn*128 + lcol];
        #pragma unroll
        for (int i = 0; i < 4; ++i)
          lds_put16(lds_, lrow + i, lcol, f2bf(acc[r][c][i] + bv));
      }
    }
    __syncthreads();
    sweep128(lds_, GC + (size_t)(bm*128) * 1024 + bn*128, 1024, tid);
  }
}

// ---------------- proj-2 + residual sum: xsum(bf16) = O2@wp2 + bp2 + x1 + o1 ----------------
__global__ __launch_bounds__(256, 3) void gemm_projadd(
    const u16* __restrict__ A, const u16* __restrict__ Bt,
    const float* __restrict__ bias, const float* __restrict__ x1,
    const u16* __restrict__ o1b, u16* __restrict__ xsum)
{
  TILE_MAP((int)blockIdx.x, bm, bn)
  int tid = threadIdx.x, wv = tid >> 6, lane = tid & 63, quad = lane >> 4, lc = lane & 15;
  int wm = wv & 1, wn = wv >> 1;
  __shared__ __align__(16) char lds_[32768];
  v4f acc[4][4] = {};
  gemm_core(A, Bt, 1024, lds_, lds_ + 16384, bm, bn, tid, acc);
  __syncthreads();
  #pragma unroll
  for (int r = 0; r < 4; ++r) {
    int lrow = wm*64 + r*16 + quad*4;
    int grow = bm*128 + lrow;
    #pragma unroll
    for (int c = 0; c < 4; ++c) {
      int lcol = wn*64 + c*16 + lc;
      int gcol = bn*128 + lcol;
      float bv = bias[gcol];
      #pragma unroll
      for (int i = 0; i < 4; ++i) {
        size_t idx = (size_t)(grow + i) * 1024 + gcol;
        lds_put16(lds_, lrow + i, lcol, f2bf(acc[r][c][i] + bv + x1[idx] + bf2f(o1b[idx])));
      }
    }
  }
  __syncthreads();
  sweep128(lds_, xsum + (size_t)(bm*128) * 1024 + bn*128, 1024, tid);
}

// ---------------- fc1: bias + fast GELU (exp2), bf16 out, N=4096, full-line stores ----------------
__global__ __launch_bounds__(256, 2) void gemm_fc1(
    const u16* __restrict__ A, const u16* __restrict__ Bt,
    const float* __restrict__ bias, u16* __restrict__ C)
{
  int bm = blockIdx.x >> 5, bn = blockIdx.x & 31;
  int tid = threadIdx.x, wv = tid >> 6, lane = tid & 63, quad = lane >> 4, lc = lane & 15;
  int wm = wv & 1, wn = wv >> 1;
  __shared__ __align__(16) char lds_[32768];
  v4f acc[4][4] = {};
  gemm_core(A, Bt, 1024, lds_, lds_ + 16384, bm, bn, tid, acc);
  __syncthreads();
  #pragma unroll
  for (int r = 0; r < 4; ++r) {
    int lrow = wm*64 + r*16 + quad*4;
    #pragma unroll
    for (int c = 0; c < 4; ++c) {
      int lcol = wn*64 + c*16 + lc;
      float bv = bias[bn*128 + lcol];
      #pragma unroll
      for (int i = 0; i < 4; ++i) {
        float v = acc[r][c][i] + bv;
        // gelu = v * t/(t+1), t = 2^{2.302384*(v+0.044715 v^3)}  (exp const folded)
        float u2 = fminf(2.3023840f * (v + 0.044715f * v * v * v), 115.f);
        float t = ex2(u2);
        lds_put16(lds_, lrow + i, lcol, f2bf(v * t / (t + 1.f)));
      }
    }
  }
  __syncthreads();
  sweep128(lds_, C + (size_t)(bm*128) * 4096 + bn*128, 4096, tid);
}

// ---------------- fc2: bias + residual(bf16), fp32 out, K=4096 ----------------
__global__ __launch_bounds__(256, 3) void gemm_fc2(
    const u16* __restrict__ A, const u16* __restrict__ Bt,
    const float* __restrict__ bias, const u16* __restrict__ r1,
    float* __restrict__ C)
{
  TILE_MAP((int)blockIdx.x, bm, bn)
  int tid = threadIdx.x, wv = tid >> 6, lane = tid & 63, quad = lane >> 4, lc = lane & 15;
  int wm = wv & 1, wn = wv >> 1;
  __shared__ __align__(16) char lds_[32768];
  v4f acc[4][4] = {};
  gemm_core(A, Bt, 4096, lds_, lds_ + 16384, bm, bn, tid, acc);
  #pragma unroll
  for (int r = 0; r < 4; ++r) {
    int grow = bm*128 + wm*64 + r*16 + quad*4;
    #pragma unroll
    for (int c = 0; c < 4; ++c) {
      int gcol = bn*128 + wn*64 + c*16 + lc;
      float bv = bias[gcol];
      #pragma unroll
      for (int i = 0; i < 4; ++i) {
        size_t idx = (size_t)(grow + i) * 1024 + gcol;
        C[idx] = acc[r][c][i] + bv + bf2f(r1[idx]);
      }
    }
  }
}

// ---------------- host ----------------
extern "C" void kernel_launch(void* const* d_in, const int* in_sizes, int n_in,
                              void* d_out, int out_size, void* d_ws, size_t ws_size,
                              hipStream_t stream)
{
  const float* x1    = (const float*)d_in[0];
  const float* x2    = (const float*)d_in[1];
  const float* x3    = (const float*)d_in[2];
  const float* ln11g = (const float*)d_in[3];
  const float* ln11b = (const float*)d_in[4];
  const float* ln12g = (const float*)d_in[5];
  const float* ln12b = (const float*)d_in[6];
  const float* ln21g = (const float*)d_in[7];
  const float* ln21b = (const float*)d_in[8];
  const float* ln23g = (const float*)d_in[9];
  const float* ln23b = (const float*)d_in[10];
  const float* ln2g  = (const float*)d_in[11];
  const float* ln2b  = (const float*)d_in[12];
  const float* a1wq  = (const float*)d_in[13];
  const float* a1wk  = (const float*)d_in[14];
  const float* a1wv  = (const float*)d_in[15];
  const float* a1wp  = (const float*)d_in[16];
  const float* a1bp  = (const float*)d_in[17];
  const float* a2wq  = (const float*)d_in[18];
  const float* a2wk  = (const float*)d_in[19];
  const float* a2wv  = (const float*)d_in[20];
  const float* a2wp  = (const float*)d_in[21];
  const float* a2bp  = (const float*)d_in[22];
  const float* fc1w  = (const float*)d_in[23];
  const float* fc1b  = (const float*)d_in[24];
  const float* fc2w  = (const float*)d_in[25];
  const float* fc2b  = (const float*)d_in[26];

  char* ws = (char*)d_ws;
  const size_t MB = (size_t)1 << 20;
  // weights (persistent, 0-32 MB)
  u16* wtq1 = (u16*)(ws + 0*MB);  u16* wtk1 = (u16*)(ws + 2*MB);
  u16* wtv1 = (u16*)(ws + 4*MB);  u16* wtp1 = (u16*)(ws + 6*MB);
  u16* wtq2 = (u16*)(ws + 8*MB);  u16* wtk2 = (u16*)(ws + 10*MB);
  u16* wtv2 = (u16*)(ws + 12*MB); u16* wtp2 = (u16*)(ws + 14*MB);
  u16* wtf1 = (u16*)(ws + 16*MB); u16* wtf2 = (u16*)(ws + 24*MB);
  // activations (liveness-overlapped; peak 144 MB)
  u16* xq1  = (u16*)(ws + 32*MB); u16* xkv1 = (u16*)(ws + 48*MB);
  u16* xq2  = (u16*)(ws + 64*MB); u16* xkv2 = (u16*)(ws + 80*MB);
  u16* Qb   = (u16*)(ws + 96*MB); u16* Kb   = (u16*)(ws + 112*MB);
  u16* VTb  = (u16*)(ws + 128*MB);
  u16* O1   = (u16*)(ws + 32*MB);                 // over xq1 (dead after g1)
  u16* O2   = (u16*)(ws + 48*MB);                 // over xkv1 (dead after g1)
  u16* o1b  = (u16*)(ws + 64*MB);                 // over xq2 (dead after g2), bf16
  u16* xsum = (u16*)(ws + 112*MB);                // bf16, over Kb (dead after attn2)
  u16* ln2o = (u16*)(ws + 32*MB);                 // over O1 (dead after proj1)
  u16* hbuf = (u16*)(ws + 48*MB);                 // 48-112 (all dead by fc1)

  dim3 blk(256);

  // D0: qkv1 prerequisites — 3 transposes + dual-LN(x1) + LN(x2)
  PrepA pa;
  {
    const float* Ws[3] = {a1wq, a1wk, a1wv};
    u16* WTs[3]        = {wtq1, wtk1, wtv1};
    int ts = 0;
    for (int i = 0; i < 3; ++i) { pa.d[i] = {Ws[i], WTs[i], 1024, 1024, ts}; ts += 1024; }
    pa.tsa = ts;   // 3072
  }
  pa.x1 = x1; pa.g11 = ln11g; pa.b11 = ln11b; pa.g21 = ln21g; pa.b21 = ln21b;
  pa.x2 = x2; pa.g12 = ln12g; pa.b12 = ln12b;
  pa.xq1 = xq1; pa.xq2 = xq2; pa.xkv1 = xkv1;
  prep_a_kernel<<<pa.tsa + 16384, blk, 0, stream>>>(pa);

  // D1: branch-1 Q/K/VT  ||  remaining prep (7 transposes + LN(x3))
  QkvArgs g1;
  g1.A[0]=xq1;  g1.Bt[0]=wtq1; g1.C[0]=Qb;
  g1.A[1]=xkv1; g1.Bt[1]=wtk1; g1.C[1]=Kb;
  g1.A[2]=xkv1; g1.Bt[2]=wtv1; g1.C[2]=VTb;
  PrepB pb;
  {
    const float* Ws[7] = {a1wp, a2wq, a2wk, a2wv, a2wp, fc1w, fc2w};
    u16* WTs[7]        = {wtp1, wtq2, wtk2, wtv2, wtp2, wtf1, wtf2};
    int Kd[7] = {1024,1024,1024,1024,1024,1024,4096};
    int Nd[7] = {1024,1024,1024,1024,1024,4096,1024};
    int ts = 0;
    for (int i = 0; i < 7; ++i) {
      pb.d[i] = {Ws[i], WTs[i], Kd[i], Nd[i], ts};
      ts += (Kd[i]/32) * (Nd[i]/32);
    }
    pb.tsb = ts;   // 13312
  }
  pb.x3 = x3; pb.g23 = ln23g; pb.b23 = ln23b; pb.xkv2 = xkv2;
  qkv_prep_kernel<<<1536 + pb.tsb + 8192, blk, 0, stream>>>(g1, pb);

  // D2: attention 1
  attn_kernel<<<2048, blk, 0, stream>>>(Qb, Kb, VTb, O1);

  // D3: branch-2 Q/K/VT (reuses Qb/Kb/VTb)
  QkvArgs g2;
  g2.A[0]=xq2;  g2.Bt[0]=wtq2; g2.C[0]=Qb;
  g2.A[1]=xkv2; g2.Bt[1]=wtk2; g2.C[1]=Kb;
  g2.A[2]=xkv2; g2.Bt[2]=wtv2; g2.C[2]=VTb;
  gemm_qkv<<<1536, blk, 0, stream>>>(g2);

  // D4: attention 2  ||  proj-1 (o1 = O1@wp1 + bp1, bf16)
  attn_proj_kernel<<<2048 + 512, blk, 0, stream>>>(Qb, Kb, VTb, O2, O1, wtp1, a1bp, o1b);

  // D5: proj-2 + residual sum -> xsum (bf16)
  gemm_projadd<<<512, blk, 0, stream>>>(O2, wtp2, a2bp, x1, o1b, xsum);

  // D6: LN2 -> bf16
  ln_bf16_kernel<<<8192, blk, 0, stream>>>(xsum, ln2g, ln2b, ln2o);

  // D7: fc1 + GELU
  gemm_fc1<<<2048, blk, 0, stream>>>(ln2o, wtf1, fc1b, hbuf);

  // D8: fc2 + bias + residual -> d_out (fp32)
  gemm_fc2<<<512, blk, 0, stream>>>(hbuf, wtf2, fc2b, xsum, (float*)d_out);
}

// Round 4
// 693.207 us; speedup vs baseline: 1.0283x; 1.0004x over previous
//
#include <hip/hip_runtime.h>
#include <hip/hip_bf16.h>
#include <cstdint>

typedef unsigned short u16;
typedef __bf16 v8bf __attribute__((ext_vector_type(8)));
typedef short v4s __attribute__((ext_vector_type(4)));
typedef float v4f __attribute__((ext_vector_type(4)));

__device__ __forceinline__ u16 f2bf(float f) {
  union { float f; uint32_t u; } v; v.f = f;
  return (u16)((v.u + 0x7fffu + ((v.u >> 16) & 1u)) >> 16);
}
__device__ __forceinline__ float bf2f(u16 u) {
  union { uint32_t u; float f; } v; v.u = ((uint32_t)u) << 16; return v.f;
}
// hardware 2^x (v_exp_f32)
__device__ __forceinline__ float ex2(float x) {
  float r; asm("v_exp_f32 %0, %1" : "=v"(r) : "v"(x)); return r;
}

// async global->LDS, 16B per lane; LDS dest = wave-uniform base + lane*16
#define GLL16(gsrc, ldst) \
  __builtin_amdgcn_global_load_lds((__attribute__((address_space(1))) void*)(gsrc), \
      (__attribute__((address_space(3))) void*)(ldst), 16, 0, 0)

// XCD-aware tile map (64 bm-tiles, M=8192): XCD (blk%8) owns a contiguous
// 8-row bm band; co-resident blocks sweep bn in lockstep.
#define TILE_MAP(blk, bm, bn) \
  int bm = ((blk) & 7) * 8 + (((blk) >> 3) & 7); \
  int bn = (blk) >> 6;

// ---------------- GEMM core (128x128 tile, BK=64, XOR-swizzled LDS) ----------------
__device__ __forceinline__ void gemm_core(
    const u16* __restrict__ A, const u16* __restrict__ Bt, int K,
    char* la, char* lb, int bm, int bn, int tid, v4f acc[4][4])
{
  int wv = tid >> 6, lane = tid & 63, quad = lane >> 4, lc = lane & 15;
  int wm = wv & 1, wn = wv >> 1;
  for (int kt = 0; kt < K; kt += 64) {
    __syncthreads();
    #pragma unroll
    for (int c0 = 0; c0 < 4; ++c0) {
      int chunk = wv*4 + c0;
      int off = chunk*1024 + lane*16;
      int row = off >> 7;
      int sc  = (off >> 4) & 7;
      int lg  = sc ^ (row & 7);
      GLL16(A  + (size_t)(bm*128 + row) * K + kt + lg*8, la + chunk*1024);
      GLL16(Bt + (size_t)(bn*128 + row) * K + kt + lg*8, lb + chunk*1024);
    }
    __syncthreads();
    #pragma unroll
    for (int kc = 0; kc < 2; ++kc) {
      v8bf af[4], bfr[4];
      #pragma unroll
      for (int r = 0; r < 4; ++r) {
        int row = wm*64 + r*16 + lc;
        int sc = (kc*4 + quad) ^ (row & 7);
        af[r] = *(const v8bf*)(la + row*128 + sc*16);
      }
      #pragma unroll
      for (int c = 0; c < 4; ++c) {
        int row = wn*64 + c*16 + lc;
        int sc = (kc*4 + quad) ^ (row & 7);
        bfr[c] = *(const v8bf*)(lb + row*128 + sc*16);
      }
      #pragma unroll
      for (int r = 0; r < 4; ++r)
        #pragma unroll
        for (int c = 0; c < 4; ++c)
          acc[r][c] = __builtin_amdgcn_mfma_f32_16x16x32_bf16(af[r], bfr[c], acc[r][c], 0, 0, 0);
    }
  }
}

// ---------------- epilogue: swizzled 128x128 bf16 LDS tile + full-line stores ----------------
__device__ __forceinline__ void lds_put16(char* lds_, int row, int col, u16 v) {
  *(u16*)(lds_ + row*256 + (((col >> 4) ^ (row & 7)) << 5) + (col & 15)*2) = v;
}
__device__ __forceinline__ void sweep128(const char* lds_, u16* gout, size_t ldc, int tid) {
  int sub = tid >> 4, j = tid & 15;
  #pragma unroll
  for (int p = 0; p < 8; ++p) {
    int row = p*16 + sub;
    uint4 d = *(const uint4*)(lds_ + row*256 + ((((j >> 1) ^ (row & 7)) << 5) + ((j & 1) << 4)));
    *(uint4*)(gout + (size_t)row*ldc + j*8) = d;
  }
}

// ---------------- prep helpers ----------------
struct TDesc { const float* W; u16* WT; int K, N, tstart; };

__device__ __forceinline__ void do_transpose(const TDesc& D, int loc, int tid, float* sh) {
  const float* W = D.W;
  u16* WT = D.WT;
  int K = D.K, N = D.N;
  int tiles_n = N >> 5;
  int bn = loc % tiles_n, bk = loc / tiles_n;
  int tx = tid & 31, ty = tid >> 5;
  #pragma unroll
  for (int j = 0; j < 4; ++j)
    sh[(ty + j*8)*33 + tx] = W[(size_t)(bk*32 + ty + j*8) * N + bn*32 + tx];
  __syncthreads();
  #pragma unroll
  for (int j = 0; j < 4; ++j)
    WT[(size_t)(bn*32 + ty + j*8) * K + bk*32 + tx] = f2bf(sh[tx*33 + ty + j*8]);
}

__device__ __forceinline__ void ln_f32_row(const float* x, const float* g, const float* b,
                                           u16* out, int row, int tid, float* red)
{
  float4 v = ((const float4*)(x + (size_t)row * 1024))[tid];
  float s = v.x + v.y + v.z + v.w;
  float ss = v.x*v.x + v.y*v.y + v.z*v.z + v.w*v.w;
  for (int d = 1; d < 64; d <<= 1) { s += __shfl_xor(s, d); ss += __shfl_xor(ss, d); }
  int wv = tid >> 6, lane = tid & 63;
  if (lane == 0) { red[wv] = s; red[4 + wv] = ss; }
  __syncthreads();
  s  = red[0] + red[1] + red[2] + red[3];
  ss = red[4] + red[5] + red[6] + red[7];
  float mean = s * (1.f/1024.f);
  float var  = ss * (1.f/1024.f) - mean*mean;
  float rs = rsqrtf(var + 1e-5f);
  float4 gv = ((const float4*)g)[tid];
  float4 bv = ((const float4*)b)[tid];
  ushort4 o;
  o.x = f2bf((v.x-mean)*rs*gv.x + bv.x);
  o.y = f2bf((v.y-mean)*rs*gv.y + bv.y);
  o.z = f2bf((v.z-mean)*rs*gv.z + bv.z);
  o.w = f2bf((v.w-mean)*rs*gv.w + bv.w);
  ((ushort4*)out)[(size_t)row*256 + tid] = o;
}

__device__ __forceinline__ void ln_f32_row2(const float* x,
    const float* g1, const float* b1, const float* g2, const float* b2,
    u16* o1, u16* o2, int row, int tid, float* red)
{
  float4 v = ((const float4*)(x + (size_t)row * 1024))[tid];
  float s = v.x + v.y + v.z + v.w;
  float ss = v.x*v.x + v.y*v.y + v.z*v.z + v.w*v.w;
  for (int d = 1; d < 64; d <<= 1) { s += __shfl_xor(s, d); ss += __shfl_xor(ss, d); }
  int wv = tid >> 6, lane = tid & 63;
  if (lane == 0) { red[wv] = s; red[4 + wv] = ss; }
  __syncthreads();
  s  = red[0] + red[1] + red[2] + red[3];
  ss = red[4] + red[5] + red[6] + red[7];
  float mean = s * (1.f/1024.f);
  float var  = ss * (1.f/1024.f) - mean*mean;
  float rs = rsqrtf(var + 1e-5f);
  float4 xn;
  xn.x = (v.x-mean)*rs; xn.y = (v.y-mean)*rs; xn.z = (v.z-mean)*rs; xn.w = (v.w-mean)*rs;
  {
    float4 gv = ((const float4*)g1)[tid];
    float4 bv = ((const float4*)b1)[tid];
    ushort4 o;
    o.x = f2bf(xn.x*gv.x + bv.x); o.y = f2bf(xn.y*gv.y + bv.y);
    o.z = f2bf(xn.z*gv.z + bv.z); o.w = f2bf(xn.w*gv.w + bv.w);
    ((ushort4*)o1)[(size_t)row*256 + tid] = o;
  }
  {
    float4 gv = ((const float4*)g2)[tid];
    float4 bv = ((const float4*)b2)[tid];
    ushort4 o;
    o.x = f2bf(xn.x*gv.x + bv.x); o.y = f2bf(xn.y*gv.y + bv.y);
    o.z = f2bf(xn.z*gv.z + bv.z); o.w = f2bf(xn.w*gv.w + bv.w);
    ((ushort4*)o2)[(size_t)row*256 + tid] = o;
  }
}

// ---------------- prep: all 10 transposes + dual-LN(x1) + LN(x2) + LN(x3) ----------------
// standalone dispatch: small LDS, no launch_bounds min -> high occupancy for the
// latency-bound tiny blocks (R3 lesson: don't cap these at the GEMM's 3/CU).
struct PrepAll {
  TDesc d[10];
  const float *x1, *g11, *b11, *g21, *b21;
  const float *x2, *g12, *b12;
  const float *x3, *g23, *b23;
  u16 *xq1, *xq2, *xkv1, *xkv2;
  int ts;
};
__global__ __launch_bounds__(256) void prep_all_kernel(PrepAll P)
{
  __shared__ float sh[32*33];
  int tid = threadIdx.x;
  int bi = blockIdx.x;
  if (bi < P.ts) {
    int idx = 0;
    #pragma unroll
    for (int i = 1; i < 10; ++i) if (bi >= P.d[i].tstart) idx = i;
    do_transpose(P.d[idx], bi - P.d[idx].tstart, tid, sh);
  } else {
    int lid = bi - P.ts;
    if (lid < 8192)
      ln_f32_row2(P.x1, P.g11, P.b11, P.g21, P.b21, P.xq1, P.xq2, lid, tid, sh);
    else if (lid < 16384)
      ln_f32_row(P.x2, P.g12, P.b12, P.xkv1, lid - 8192, tid, sh);
    else
      ln_f32_row(P.x3, P.g23, P.b23, P.xkv2, lid - 16384, tid, sh);
  }
}

// ---------------- LayerNorm with bf16 input: bf16 row -> bf16 row ----------------
__global__ __launch_bounds__(256) void ln_bf16_kernel(
    const u16* __restrict__ x, const float* __restrict__ g, const float* __restrict__ bt,
    u16* __restrict__ out)
{
  int row = blockIdx.x, tid = threadIdx.x;
  ushort4 xr = ((const ushort4*)x)[(size_t)row*256 + tid];
  float4 v;
  v.x = bf2f(xr.x); v.y = bf2f(xr.y); v.z = bf2f(xr.z); v.w = bf2f(xr.w);
  float s = v.x + v.y + v.z + v.w;
  float ss = v.x*v.x + v.y*v.y + v.z*v.z + v.w*v.w;
  for (int d = 1; d < 64; d <<= 1) { s += __shfl_xor(s, d); ss += __shfl_xor(ss, d); }
  __shared__ float red[8];
  int wv = tid >> 6, lane = tid & 63;
  if (lane == 0) { red[wv] = s; red[4 + wv] = ss; }
  __syncthreads();
  s  = red[0] + red[1] + red[2] + red[3];
  ss = red[4] + red[5] + red[6] + red[7];
  float mean = s * (1.f/1024.f);
  float var  = ss * (1.f/1024.f) - mean*mean;
  float rs = rsqrtf(var + 1e-5f);
  float4 gv = ((const float4*)g)[tid];
  float4 bv = ((const float4*)bt)[tid];
  ushort4 o;
  o.x = f2bf((v.x-mean)*rs*gv.x + bv.x);
  o.y = f2bf((v.y-mean)*rs*gv.y + bv.y);
  o.z = f2bf((v.z-mean)*rs*gv.z + bv.z);
  o.w = f2bf((v.w-mean)*rs*gv.w + bv.w);
  ((ushort4*)out)[(size_t)row*256 + tid] = o;
}

// ---------------- QKV GEMM body (3 subs x 512 tiles) with full-line epilogues ----------------
struct QkvArgs { const u16* A[3]; const u16* Bt[3]; u16* C[3]; };

__device__ __forceinline__ void qkv_body(const QkvArgs& P, int blk, int tid, char* lds_)
{
  int sub = blk >> 9;
  int local = blk & 511;
  TILE_MAP(local, bm, bn)
  int wv = tid >> 6, lane = tid & 63, quad = lane >> 4, lc = lane & 15;
  int wm = wv & 1, wn = wv >> 1;
  v4f acc[4][4] = {};
  gemm_core(P.A[sub], P.Bt[sub], 1024, lds_, lds_ + 16384, bm, bn, tid, acc);
  u16* Cout = P.C[sub];
  __syncthreads();
  if (sub == 2) {
    // VT: transposed tile in LDS (lds row = d-col), rows stream 256B into VT
    #pragma unroll
    for (int r = 0; r < 4; ++r) {
      int rl = wm*64 + r*16 + quad*4;
      #pragma unroll
      for (int c = 0; c < 4; ++c) {
        int cl = wn*64 + c*16 + lc;
        #pragma unroll
        for (int i = 0; i < 4; ++i)
          lds_put16(lds_, cl, rl + i, f2bf(acc[r][c][i]));
      }
    }
    __syncthreads();
    sweep128(lds_, Cout + (size_t)(bn*128) * 8192 + bm*128, 8192, tid);
  } else {
    #pragma unroll
    for (int r = 0; r < 4; ++r) {
      int lrow = wm*64 + r*16 + quad*4;
      #pragma unroll
      for (int c = 0; c < 4; ++c) {
        int lcol = wn*64 + c*16 + lc;
        #pragma unroll
        for (int i = 0; i < 4; ++i)
          lds_put16(lds_, lrow + i, lcol, f2bf(acc[r][c][i]));
      }
    }
    __syncthreads();
    sweep128(lds_, Cout + (size_t)(bm*128) * 1024 + bn*128, 1024, tid);
  }
}

__global__ __launch_bounds__(256, 4) void gemm_qkv(QkvArgs P)
{
  __shared__ __align__(16) char lds_[32768];
  qkv_body(P, blockIdx.x, threadIdx.x, lds_);
}

// ---------------- Flash attention body (transposed-S, exp2-domain softmax) ----------------
__device__ __forceinline__ void attn_body(
    const u16* __restrict__ Q, const u16* __restrict__ K, const u16* __restrict__ VT,
    u16* __restrict__ O, int bid, int tid, char* lds_)
{
  int qt = bid & 15, h = (bid >> 4) & 15, b = bid >> 8;
  int wv = tid >> 6, lane = tid & 63, quad = lane >> 4, lc = lane & 15;
  char* kt_l = lds_;            // K tile [128 kv][64 d], 128B rows, swizzled
  char* vt_l = lds_ + 16384;    // VT tile [64 d][128 kv], 256B rows, swizzled
  const float cl2 = 0.18033688f;   // 0.125 * log2(e)

  v8bf qf[2];
  {
    int qrow = qt*64 + wv*16 + lc;
    const u16* qp = Q + ((size_t)(b*1024 + qrow) * 1024 + h*64 + quad*8);
    qf[0] = *(const v8bf*)qp;
    qf[1] = *(const v8bf*)(qp + 32);
  }

  float m_i = -1e30f, l_i = 0.f;
  v4f oacc[4] = {};

  for (int it = 0; it < 8; ++it) {
    int kvb = it * 128;
    __syncthreads();
    #pragma unroll
    for (int c0 = 0; c0 < 4; ++c0) {
      int ch = wv*4 + c0;
      int off = ch*1024 + lane*16;
      {
        int row = off >> 7, sc = (off >> 4) & 7, lg = sc ^ (row & 7);
        GLL16(K + (size_t)(b*1024 + kvb + row) * 1024 + h*64 + lg*8, kt_l + ch*1024);
      }
      {
        int row = off >> 8, sc = (off >> 4) & 15, lg = sc ^ (row & 15);
        GLL16(VT + (size_t)(h*64 + row) * 8192 + b*1024 + kvb + lg*8, vt_l + ch*1024);
      }
    }
    __syncthreads();

    v4f s[8] = {};
    #pragma unroll
    for (int ct = 0; ct < 8; ++ct) {
      int row = ct*16 + lc;
      #pragma unroll
      for (int kc = 0; kc < 2; ++kc) {
        int sc = (kc*4 + quad) ^ (row & 7);
        v8bf kf = *(const v8bf*)(kt_l + row*128 + sc*16);
        s[ct] = __builtin_amdgcn_mfma_f32_16x16x32_bf16(kf, qf[kc], s[ct], 0, 0, 0);
      }
    }

    #pragma unroll
    for (int ct = 0; ct < 8; ++ct)
      #pragma unroll
      for (int i = 0; i < 4; ++i) s[ct][i] *= cl2;
    float mx = m_i;
    #pragma unroll
    for (int ct = 0; ct < 8; ++ct)
      #pragma unroll
      for (int i = 0; i < 4; ++i) mx = fmaxf(mx, s[ct][i]);
    mx = fmaxf(mx, __shfl_xor(mx, 16));
    mx = fmaxf(mx, __shfl_xor(mx, 32));
    float alpha = ex2(m_i - mx);
    float rs = 0.f;
    #pragma unroll
    for (int ct = 0; ct < 8; ++ct)
      #pragma unroll
      for (int i = 0; i < 4; ++i) {
        float p = ex2(s[ct][i] - mx);
        s[ct][i] = p;
        rs += p;
      }
    rs += __shfl_xor(rs, 16);
    rs += __shfl_xor(rs, 32);
    l_i = l_i * alpha + rs;
    m_i = mx;
    #pragma unroll
    for (int dt = 0; dt < 4; ++dt)
      #pragma unroll
      for (int i = 0; i < 4; ++i) oacc[dt][i] *= alpha;

    #pragma unroll
    for (int ct = 0; ct < 8; ++ct) {
      v4s pfrag;
      #pragma unroll
      for (int i = 0; i < 4; ++i) pfrag[i] = (short)f2bf(s[ct][i]);
      int lg = ct*2 + (quad >> 1);
      int ho = (quad & 1) * 8;
      #pragma unroll
      for (int dt = 0; dt < 4; ++dt) {
        int rowd = dt*16 + lc;
        int sc = lg ^ (rowd & 15);
        v4s vfrag = *(const v4s*)(vt_l + rowd*256 + sc*16 + ho);
        oacc[dt] = __builtin_amdgcn_mfma_f32_16x16x16bf16_1k(vfrag, pfrag, oacc[dt], 0, 0, 0);
      }
    }
  }

  __syncthreads();
  {
    char* base = kt_l + wv*2048;
    float inv = 1.f / l_i;
    #pragma unroll
    for (int dt = 0; dt < 4; ++dt) {
      ushort4 o;
      o.x = f2bf(oacc[dt][0]*inv); o.y = f2bf(oacc[dt][1]*inv);
      o.z = f2bf(oacc[dt][2]*inv); o.w = f2bf(oacc[dt][3]*inv);
      int lg = dt*2 + (quad >> 1);
      int sc = lg ^ (lc & 7);
      *(ushort4*)(base + lc*128 + sc*16 + (quad & 1)*8) = o;
    }
  }
  __syncthreads();
  {
    char* base = kt_l + wv*2048;
    #pragma unroll
    for (int rep = 0; rep < 2; ++rep) {
      int qr = rep*8 + (lane >> 3);
      int ch = lane & 7;
      int sc = ch ^ (qr & 7);
      uint4 d = *(const uint4*)(base + qr*128 + sc*16);
      *(uint4*)(O + (size_t)(b*1024 + qt*64 + wv*16 + qr) * 1024 + h*64 + ch*8) = d;
    }
  }
}

// standalone attention (fallback path)
__global__ __launch_bounds__(256, 4) void attn_kernel(
    const u16* __restrict__ Q, const u16* __restrict__ K, const u16* __restrict__ VT,
    u16* __restrict__ O)
{
  __shared__ __align__(16) char lds_[32768];
  attn_body(Q, K, VT, O, blockIdx.x, threadIdx.x, lds_);
}

// ---------------- fused attention-1 || qkv-2 (independent work, same occupancy regime) ----------------
__global__ __launch_bounds__(256, 4) void attn_qkv_kernel(
    const u16* __restrict__ Q, const u16* __restrict__ K, const u16* __restrict__ VT,
    u16* __restrict__ O, QkvArgs G)
{
  __shared__ __align__(16) char lds_[32768];
  int tid = threadIdx.x;
  if ((int)blockIdx.x < 2048)
    attn_body(Q, K, VT, O, blockIdx.x, tid, lds_);
  else
    qkv_body(G, blockIdx.x - 2048, tid, lds_);
}

// ---------------- fused attention-2 || proj-1 (bias + bf16 out, full-line stores) ----------------
__global__ __launch_bounds__(256, 4) void attn_proj_kernel(
    const u16* __restrict__ Q, const u16* __restrict__ K, const u16* __restrict__ VT,
    u16* __restrict__ O,
    const u16* __restrict__ GA, const u16* __restrict__ GBt,
    const float* __restrict__ Gbias, u16* __restrict__ GC)
{
  __shared__ __align__(16) char lds_[32768];
  int tid = threadIdx.x;
  if ((int)blockIdx.x < 2048) {
    attn_body(Q, K, VT, O, blockIdx.x, tid, lds_);
  } else {
    int local = blockIdx.x - 2048;
    TILE_MAP(local, bm, bn)
    int wv = tid >> 6, lane = tid & 63, quad = lane >> 4, lc = lane & 15;
    int wm = wv & 1, wn = wv >> 1;
    v4f acc[4][4] = {};
    gemm_core(GA, GBt, 1024, lds_, lds_ + 16384, bm, bn, tid, acc);
    __syncthreads();
    #pragma unroll
    for (int r = 0; r < 4; ++r) {
      int lrow = wm*64 + r*16 + quad*4;
      #pragma unroll
      for (int c = 0; c < 4; ++c) {
        int lcol = wn*64 + c*16 + lc;
        float bv = Gbias[bn*128 + lcol];
        #pragma unroll
        for (int i = 0; i < 4; ++i)
          lds_put16(lds_, lrow + i, lcol, f2bf(acc[r][c][i] + bv));
      }
    }
    __syncthreads();
    sweep128(lds_, GC + (size_t)(bm*128) * 1024 + bn*128, 1024, tid);
  }
}

// ---------------- proj-2 + residual sum: xsum(bf16) = O2@wp2 + bp2 + x1 + o1 ----------------
__global__ __launch_bounds__(256, 4) void gemm_projadd(
    const u16* __restrict__ A, const u16* __restrict__ Bt,
    const float* __restrict__ bias, const float* __restrict__ x1,
    const u16* __restrict__ o1b, u16* __restrict__ xsum)
{
  TILE_MAP((int)blockIdx.x, bm, bn)
  int tid = threadIdx.x, wv = tid >> 6, lane = tid & 63, quad = lane >> 4, lc = lane & 15;
  int wm = wv & 1, wn = wv >> 1;
  __shared__ __align__(16) char lds_[32768];
  v4f acc[4][4] = {};
  gemm_core(A, Bt, 1024, lds_, lds_ + 16384, bm, bn, tid, acc);
  __syncthreads();
  #pragma unroll
  for (int r = 0; r < 4; ++r) {
    int lrow = wm*64 + r*16 + quad*4;
    int grow = bm*128 + lrow;
    #pragma unroll
    for (int c = 0; c < 4; ++c) {
      int lcol = wn*64 + c*16 + lc;
      int gcol = bn*128 + lcol;
      float bv = bias[gcol];
      #pragma unroll
      for (int i = 0; i < 4; ++i) {
        size_t idx = (size_t)(grow + i) * 1024 + gcol;
        lds_put16(lds_, lrow + i, lcol, f2bf(acc[r][c][i] + bv + x1[idx] + bf2f(o1b[idx])));
      }
    }
  }
  __syncthreads();
  sweep128(lds_, xsum + (size_t)(bm*128) * 1024 + bn*128, 1024, tid);
}

// ---------------- fc1: bias + fast GELU (exp2), bf16 out, N=4096, full-line stores ----------------
__global__ __launch_bounds__(256, 2) void gemm_fc1(
    const u16* __restrict__ A, const u16* __restrict__ Bt,
    const float* __restrict__ bias, u16* __restrict__ C)
{
  int bm = blockIdx.x >> 5, bn = blockIdx.x & 31;
  int tid = threadIdx.x, wv = tid >> 6, lane = tid & 63, quad = lane >> 4, lc = lane & 15;
  int wm = wv & 1, wn = wv >> 1;
  __shared__ __align__(16) char lds_[32768];
  v4f acc[4][4] = {};
  gemm_core(A, Bt, 1024, lds_, lds_ + 16384, bm, bn, tid, acc);
  __syncthreads();
  #pragma unroll
  for (int r = 0; r < 4; ++r) {
    int lrow = wm*64 + r*16 + quad*4;
    #pragma unroll
    for (int c = 0; c < 4; ++c) {
      int lcol = wn*64 + c*16 + lc;
      float bv = bias[bn*128 + lcol];
      #pragma unroll
      for (int i = 0; i < 4; ++i) {
        float v = acc[r][c][i] + bv;
        float u2 = fminf(2.3023840f * (v + 0.044715f * v * v * v), 115.f);
        float t = ex2(u2);
        lds_put16(lds_, lrow + i, lcol, f2bf(v * t / (t + 1.f)));
      }
    }
  }
  __syncthreads();
  sweep128(lds_, C + (size_t)(bm*128) * 4096 + bn*128, 4096, tid);
}

// ---------------- fc2: bias + residual(bf16), fp32 out, K=4096 ----------------
__global__ __launch_bounds__(256, 3) void gemm_fc2(
    const u16* __restrict__ A, const u16* __restrict__ Bt,
    const float* __restrict__ bias, const u16* __restrict__ r1,
    float* __restrict__ C)
{
  TILE_MAP((int)blockIdx.x, bm, bn)
  int tid = threadIdx.x, wv = tid >> 6, lane = tid & 63, quad = lane >> 4, lc = lane & 15;
  int wm = wv & 1, wn = wv >> 1;
  __shared__ __align__(16) char lds_[32768];
  v4f acc[4][4] = {};
  gemm_core(A, Bt, 4096, lds_, lds_ + 16384, bm, bn, tid, acc);
  #pragma unroll
  for (int r = 0; r < 4; ++r) {
    int grow = bm*128 + wm*64 + r*16 + quad*4;
    #pragma unroll
    for (int c = 0; c < 4; ++c) {
      int gcol = bn*128 + wn*64 + c*16 + lc;
      float bv = bias[gcol];
      #pragma unroll
      for (int i = 0; i < 4; ++i) {
        size_t idx = (size_t)(grow + i) * 1024 + gcol;
        C[idx] = acc[r][c][i] + bv + bf2f(r1[idx]);
      }
    }
  }
}

// ---------------- host ----------------
extern "C" void kernel_launch(void* const* d_in, const int* in_sizes, int n_in,
                              void* d_out, int out_size, void* d_ws, size_t ws_size,
                              hipStream_t stream)
{
  const float* x1    = (const float*)d_in[0];
  const float* x2    = (const float*)d_in[1];
  const float* x3    = (const float*)d_in[2];
  const float* ln11g = (const float*)d_in[3];
  const float* ln11b = (const float*)d_in[4];
  const float* ln12g = (const float*)d_in[5];
  const float* ln12b = (const float*)d_in[6];
  const float* ln21g = (const float*)d_in[7];
  const float* ln21b = (const float*)d_in[8];
  const float* ln23g = (const float*)d_in[9];
  const float* ln23b = (const float*)d_in[10];
  const float* ln2g  = (const float*)d_in[11];
  const float* ln2b  = (const float*)d_in[12];
  const float* a1wq  = (const float*)d_in[13];
  const float* a1wk  = (const float*)d_in[14];
  const float* a1wv  = (const float*)d_in[15];
  const float* a1wp  = (const float*)d_in[16];
  const float* a1bp  = (const float*)d_in[17];
  const float* a2wq  = (const float*)d_in[18];
  const float* a2wk  = (const float*)d_in[19];
  const float* a2wv  = (const float*)d_in[20];
  const float* a2wp  = (const float*)d_in[21];
  const float* a2bp  = (const float*)d_in[22];
  const float* fc1w  = (const float*)d_in[23];
  const float* fc1b  = (const float*)d_in[24];
  const float* fc2w  = (const float*)d_in[25];
  const float* fc2b  = (const float*)d_in[26];

  char* ws = (char*)d_ws;
  const size_t MB = (size_t)1 << 20;
  // weights (persistent, 0-32 MB)
  u16* wtq1 = (u16*)(ws + 0*MB);  u16* wtk1 = (u16*)(ws + 2*MB);
  u16* wtv1 = (u16*)(ws + 4*MB);  u16* wtp1 = (u16*)(ws + 6*MB);
  u16* wtq2 = (u16*)(ws + 8*MB);  u16* wtk2 = (u16*)(ws + 10*MB);
  u16* wtv2 = (u16*)(ws + 12*MB); u16* wtp2 = (u16*)(ws + 14*MB);
  u16* wtf1 = (u16*)(ws + 16*MB); u16* wtf2 = (u16*)(ws + 24*MB);
  // activations
  u16* xq1  = (u16*)(ws + 32*MB); u16* xkv1 = (u16*)(ws + 48*MB);
  u16* xq2  = (u16*)(ws + 64*MB); u16* xkv2 = (u16*)(ws + 80*MB);
  u16* Qb   = (u16*)(ws + 96*MB); u16* Kb   = (u16*)(ws + 112*MB);
  u16* VTb  = (u16*)(ws + 128*MB);
  u16* O1   = (u16*)(ws + 32*MB);                 // over xq1 (dead after qkv1)
  u16* o1b  = (u16*)(ws + 64*MB);                 // over xq2 (dead after qkv2)
  u16* xsum = (u16*)(ws + 112*MB);                // over Kb/K1 (dead in both paths)
  u16* ln2o = (u16*)(ws + 32*MB);                 // over O1 (dead after proj1)
  u16* hbuf = (u16*)(ws + 48*MB);                 // 48-112 (all dead by fc1)

  // D2/D3 fusion needs separate branch-2 Q/K/VT buffers (peak 176 MB); fall back
  // to the sequential 144 MB layout if the workspace is too small.
  bool fused23 = (ws_size >= (size_t)176 * MB);
  u16 *Q2, *K2, *VT2, *O2;
  if (fused23) {
    Q2  = (u16*)(ws + 48*MB);    // over xkv1 (dead after qkv1)
    K2  = (u16*)(ws + 144*MB);
    VT2 = (u16*)(ws + 160*MB);
    O2  = (u16*)(ws + 96*MB);    // over Qb/Q1 (dead after attn1)
  } else {
    Q2 = Qb; K2 = Kb; VT2 = VTb;
    O2  = (u16*)(ws + 48*MB);    // over xkv1 (dead after qkv1)
  }

  dim3 blk(256);

  // D0: all prep — 10 transposes + dual-LN(x1) + LN(x2) + LN(x3)
  PrepAll pa;
  {
    const float* Ws[10]  = {a1wq, a1wk, a1wv, a1wp, a2wq, a2wk, a2wv, a2wp, fc1w, fc2w};
    u16* WTs[10]         = {wtq1, wtk1, wtv1, wtp1, wtq2, wtk2, wtv2, wtp2, wtf1, wtf2};
    int Kd[10] = {1024,1024,1024,1024,1024,1024,1024,1024,1024,4096};
    int Nd[10] = {1024,1024,1024,1024,1024,1024,1024,1024,4096,1024};
    int ts = 0;
    for (int i = 0; i < 10; ++i) {
      pa.d[i] = {Ws[i], WTs[i], Kd[i], Nd[i], ts};
      ts += (Kd[i]/32) * (Nd[i]/32);
    }
    pa.ts = ts;   // 16384
  }
  pa.x1 = x1; pa.g11 = ln11g; pa.b11 = ln11b; pa.g21 = ln21g; pa.b21 = ln21b;
  pa.x2 = x2; pa.g12 = ln12g; pa.b12 = ln12b;
  pa.x3 = x3; pa.g23 = ln23g; pa.b23 = ln23b;
  pa.xq1 = xq1; pa.xq2 = xq2; pa.xkv1 = xkv1; pa.xkv2 = xkv2;
  prep_all_kernel<<<pa.ts + 24576, blk, 0, stream>>>(pa);

  // D1: branch-1 Q/K/VT
  QkvArgs g1;
  g1.A[0]=xq1;  g1.Bt[0]=wtq1; g1.C[0]=Qb;
  g1.A[1]=xkv1; g1.Bt[1]=wtk1; g1.C[1]=Kb;
  g1.A[2]=xkv1; g1.Bt[2]=wtv1; g1.C[2]=VTb;
  gemm_qkv<<<1536, blk, 0, stream>>>(g1);

  // D2(+D3): attention 1  ||  branch-2 Q/K/VT (independent; fused when ws allows)
  QkvArgs g2;
  g2.A[0]=xq2;  g2.Bt[0]=wtq2; g2.C[0]=Q2;
  g2.A[1]=xkv2; g2.Bt[1]=wtk2; g2.C[1]=K2;
  g2.A[2]=xkv2; g2.Bt[2]=wtv2; g2.C[2]=VT2;
  if (fused23) {
    attn_qkv_kernel<<<2048 + 1536, blk, 0, stream>>>(Qb, Kb, VTb, O1, g2);
  } else {
    attn_kernel<<<2048, blk, 0, stream>>>(Qb, Kb, VTb, O1);
    gemm_qkv<<<1536, blk, 0, stream>>>(g2);
  }

  // D4: attention 2  ||  proj-1 (o1 = O1@wp1 + bp1, bf16)
  attn_proj_kernel<<<2048 + 512, blk, 0, stream>>>(Q2, K2, VT2, O2, O1, wtp1, a1bp, o1b);

  // D5: proj-2 + residual sum -> xsum (bf16)
  gemm_projadd<<<512, blk, 0, stream>>>(O2, wtp2, a2bp, x1, o1b, xsum);

  // D6: LN2 -> bf16
  ln_bf16_kernel<<<8192, blk, 0, stream>>>(xsum, ln2g, ln2b, ln2o);

  // D7: fc1 + GELU
  gemm_fc1<<<2048, blk, 0, stream>>>(ln2o, wtf1, fc1b, hbuf);

  // D8: fc2 + bias + residual -> d_out (fp32)
  gemm_fc2<<<512, blk, 0, stream>>>(hbuf, wtf2, fc2b, xsum, (float*)d_out);
}